// Round 5
// baseline (1902.147 us; speedup 1.0000x reference)
//
#include <hip/hip_runtime.h>

#define NN 100000
#define NP 100096   // padded rows (782 blocks * 128)
#define NE 1000000
#define NG 1000
#define H 128
#define NLAYER 4
#define NEG 0.2f
#define SCAN_BLOCKS 98

using short8 = __attribute__((ext_vector_type(8))) short;
using fx4 = __attribute__((ext_vector_type(4))) float;

__device__ __forceinline__ float lrelu(float x) { return x >= 0.f ? x : NEG * x; }

__device__ __forceinline__ unsigned short f2bf(float f) {
    union { float f; unsigned int u; } v;
    v.f = f;
    return (unsigned short)((v.u + 0x7fffu + ((v.u >> 16) & 1u)) >> 16);
}
__device__ __forceinline__ float bf2f(unsigned short h) {
    union { unsigned int u; float f; } v;
    v.u = ((unsigned int)h) << 16;
    return v.f;
}
__device__ __forceinline__ float bflo(unsigned int u) {
    union { unsigned int x; float f; } v;
    v.x = u << 16;
    return v.f;
}
__device__ __forceinline__ float bfhi(unsigned int u) {
    union { unsigned int x; float f; } v;
    v.x = u & 0xffff0000u;
    return v.f;
}

// ---------------- Atom encoder: h[n][c] = sum_f emb[f][nfeats[n][f]][c]  (bf16 out) ----------------
__global__ __launch_bounds__(256) void k_atom(const int* __restrict__ nfeats,
                                              const float* __restrict__ emb,
                                              unsigned short* __restrict__ h) {
    int node = blockIdx.x * 4 + (threadIdx.x >> 6);
    if (node >= NN) return;
    int lane = threadIdx.x & 63;
    int c = lane * 2;
    float ax = 0.f, ay = 0.f;
#pragma unroll
    for (int f = 0; f < 9; ++f) {
        int idx = nfeats[node * 9 + f];
        float2 e = *(const float2*)(emb + (size_t)((f << 6) + idx) * H + c);
        ax += e.x;
        ay += e.y;
    }
    unsigned int packed = (unsigned int)f2bf(ax) | ((unsigned int)f2bf(ay) << 16);
    *(unsigned int*)(h + (size_t)node * H + c) = packed;
}

// ---------------- Weight prep: WT[mat][n][k] = bf16(W[mat][k][n]) ----------------
__global__ __launch_bounds__(256) void k_wt(const float* __restrict__ Wq,
                                            const float* __restrict__ Wk,
                                            const float* __restrict__ Wr,
                                            unsigned short* __restrict__ WT) {
    int mat = blockIdx.x;      // layer*3 + {0=q,1=k,2=r}
    int l = mat / 3;
    int kind = mat - l * 3;
    const float* src = (kind == 0 ? Wq : kind == 1 ? Wk : Wr) + (size_t)l * H * H;
    unsigned short* dst = WT + (size_t)mat * H * H;
    for (int idx = threadIdx.x; idx < H * H; idx += 256) {
        int kk = idx >> 7, n = idx & 127;
        dst[n * H + kk] = f2bf(src[idx]);
    }
}

// ---------------- CSR build ----------------
__global__ __launch_bounds__(256) void k_hist(const int* __restrict__ dst, int* __restrict__ deg) {
    int i = blockIdx.x * blockDim.x + threadIdx.x;
    if (i < NE) atomicAdd(&deg[dst[i]], 1);
}

__global__ __launch_bounds__(1024) void k_scan1(const int* __restrict__ deg,
                                                int* __restrict__ rowp,
                                                int* __restrict__ bsum) {
    __shared__ int tmp[1024];
    int t = threadIdx.x;
    int i = blockIdx.x * 1024 + t;
    int v = (i < NN) ? deg[i] : 0;
    tmp[t] = v;
    __syncthreads();
    for (int off = 1; off < 1024; off <<= 1) {
        int u = (t >= off) ? tmp[t - off] : 0;
        __syncthreads();
        tmp[t] += u;
        __syncthreads();
    }
    if (i < NN) rowp[i] = tmp[t] - v;  // block-local exclusive
    if (t == 1023) bsum[blockIdx.x] = tmp[1023];
}

__global__ __launch_bounds__(128) void k_scan2(int* __restrict__ bsum) {
    __shared__ int tmp[128];
    int t = threadIdx.x;
    int v = (t < SCAN_BLOCKS) ? bsum[t] : 0;
    tmp[t] = v;
    __syncthreads();
    for (int off = 1; off < 128; off <<= 1) {
        int u = (t >= off) ? tmp[t - off] : 0;
        __syncthreads();
        tmp[t] += u;
        __syncthreads();
    }
    if (t < SCAN_BLOCKS) bsum[t] = tmp[t] - v;  // exclusive block offsets
}

__global__ __launch_bounds__(256) void k_scan3(const int* __restrict__ bsum,
                                               int* __restrict__ rowp,
                                               int* __restrict__ cursor) {
    int i = blockIdx.x * blockDim.x + threadIdx.x;
    if (i < NN) {
        int v = rowp[i] + bsum[i >> 10];
        rowp[i] = v;
        cursor[i] = v;
    }
    if (i == 0) rowp[NN] = NE;
}

__global__ __launch_bounds__(256) void k_scatter(const int* __restrict__ src,
                                                 const int* __restrict__ dst,
                                                 int* __restrict__ cursor,
                                                 int* __restrict__ csr_src) {
    int i = blockIdx.x * blockDim.x + threadIdx.x;
    if (i < NE) {
        int pos = atomicAdd(&cursor[dst[i]], 1);
        csr_src[pos] = src[i];
    }
}

// ---------------- graph boundaries: gstart[g] = lower_bound(gid, g); gid is sorted ----------------
__global__ __launch_bounds__(256) void k_gbound(const int* __restrict__ gid,
                                                int* __restrict__ gstart) {
    int g = blockIdx.x * blockDim.x + threadIdx.x;
    if (g > NG) return;
    if (g == NG) { gstart[NG] = NN; return; }
    int lo = 0, hi = NN;
    while (lo < hi) {
        int mid = (lo + hi) >> 1;
        if (gid[mid] < g) lo = mid + 1; else hi = mid;
    }
    gstart[g] = lo;
}

// ---------------- fused q/k GEMM via MFMA ----------------
__global__ __launch_bounds__(256) void k_qk_mfma(const unsigned short* __restrict__ h,
                                                 const unsigned short* __restrict__ WTq,
                                                 const float* __restrict__ bq,
                                                 const unsigned short* __restrict__ WTk,
                                                 const float* __restrict__ bk,
                                                 unsigned short* __restrict__ q,
                                                 unsigned short* __restrict__ k) {
    int lane = threadIdx.x & 63;
    int wave = threadIdx.x >> 6;
    int row0 = blockIdx.x * 128 + wave * 32;
    int lrow = lane & 15;
    int lk = (lane >> 4) << 3;

    short8 a[2][4];
#pragma unroll
    for (int rt = 0; rt < 2; ++rt)
#pragma unroll
        for (int ks = 0; ks < 4; ++ks)
            a[rt][ks] = *(const short8*)(h + (size_t)(row0 + rt * 16 + lrow) * H + ks * 32 + lk);

    fx4 aq[2][8], ak[2][8];
#pragma unroll
    for (int ct = 0; ct < 8; ++ct) {
        float vq = bq[ct * 16 + lrow];
        float vk = bk[ct * 16 + lrow];
#pragma unroll
        for (int rt = 0; rt < 2; ++rt) {
            aq[rt][ct] = fx4{vq, vq, vq, vq};
            ak[rt][ct] = fx4{vk, vk, vk, vk};
        }
    }

#pragma unroll
    for (int ks = 0; ks < 4; ++ks)
#pragma unroll
        for (int ct = 0; ct < 8; ++ct) {
            short8 wq = *(const short8*)(WTq + (ct * 16 + lrow) * H + ks * 32 + lk);
            short8 wk = *(const short8*)(WTk + (ct * 16 + lrow) * H + ks * 32 + lk);
#pragma unroll
            for (int rt = 0; rt < 2; ++rt) {
                aq[rt][ct] = __builtin_amdgcn_mfma_f32_16x16x32_bf16(a[rt][ks], wq, aq[rt][ct], 0, 0, 0);
                ak[rt][ct] = __builtin_amdgcn_mfma_f32_16x16x32_bf16(a[rt][ks], wk, ak[rt][ct], 0, 0, 0);
            }
        }

#pragma unroll
    for (int rt = 0; rt < 2; ++rt)
#pragma unroll
        for (int ct = 0; ct < 8; ++ct)
#pragma unroll
            for (int rg = 0; rg < 4; ++rg) {
                int r = row0 + rt * 16 + ((lane >> 4) << 2) + rg;
                if (r < NN) {
                    q[(size_t)r * H + ct * 16 + lrow] = f2bf(aq[rt][ct][rg]);
                    k[(size_t)r * H + ct * 16 + lrow] = f2bf(ak[rt][ct][rg]);
                }
            }
}

// ---------------- h_new = lrelu(agg@Wr + br) via MFMA ----------------
__global__ __launch_bounds__(256) void k_r_mfma(const unsigned short* __restrict__ agg,
                                                const unsigned short* __restrict__ WTr,
                                                const float* __restrict__ br,
                                                unsigned short* __restrict__ hout) {
    int lane = threadIdx.x & 63;
    int wave = threadIdx.x >> 6;
    int row0 = blockIdx.x * 128 + wave * 32;
    int lrow = lane & 15;
    int lk = (lane >> 4) << 3;

    short8 a[2][4];
#pragma unroll
    for (int rt = 0; rt < 2; ++rt)
#pragma unroll
        for (int ks = 0; ks < 4; ++ks)
            a[rt][ks] = *(const short8*)(agg + (size_t)(row0 + rt * 16 + lrow) * H + ks * 32 + lk);

    fx4 acc[2][8];
#pragma unroll
    for (int ct = 0; ct < 8; ++ct) {
        float v = br[ct * 16 + lrow];
#pragma unroll
        for (int rt = 0; rt < 2; ++rt) acc[rt][ct] = fx4{v, v, v, v};
    }

#pragma unroll
    for (int ks = 0; ks < 4; ++ks)
#pragma unroll
        for (int ct = 0; ct < 8; ++ct) {
            short8 w = *(const short8*)(WTr + (ct * 16 + lrow) * H + ks * 32 + lk);
#pragma unroll
            for (int rt = 0; rt < 2; ++rt)
                acc[rt][ct] = __builtin_amdgcn_mfma_f32_16x16x32_bf16(a[rt][ks], w, acc[rt][ct], 0, 0, 0);
        }

#pragma unroll
    for (int rt = 0; rt < 2; ++rt)
#pragma unroll
        for (int ct = 0; ct < 8; ++ct)
#pragma unroll
            for (int rg = 0; rg < 4; ++rg) {
                int r = row0 + rt * 16 + ((lane >> 4) << 2) + rg;
                if (r < NN)
                    hout[(size_t)r * H + ct * 16 + lrow] = f2bf(lrelu(acc[rt][ct][rg]));
            }
}

// ---------------- aggregation (gather): agg[n] = sum_e lrelu(q[n]+k[src_e])  (bf16) ----------------
// round-3 proven version: uniform j loop, no divergent __shfl
__global__ __launch_bounds__(256) void k_agg(const unsigned short* __restrict__ q,
                                             const unsigned short* __restrict__ kk,
                                             const int* __restrict__ rowp,
                                             const int* __restrict__ csr_src,
                                             unsigned short* __restrict__ agg) {
    int node = blockIdx.x * 4 + (threadIdx.x >> 6);
    if (node >= NN) return;
    int lane = threadIdx.x & 63;
    int start = rowp[node];
    int end = rowp[node + 1];
    unsigned int qp = *(const unsigned int*)(q + (size_t)node * H + lane * 2);
    float qx = bf2f((unsigned short)(qp & 0xffff));
    float qy = bf2f((unsigned short)(qp >> 16));
    float ax = 0.f, ay = 0.f;
    for (int base = start; base < end; base += 64) {
        int cnt = end - base;
        if (cnt > 64) cnt = 64;
        int sid = (lane < cnt) ? csr_src[base + lane] : 0;
        for (int j = 0; j < cnt; ++j) {
            int s = __shfl(sid, j);
            unsigned int kp = *(const unsigned int*)(kk + (size_t)s * H + lane * 2);
            ax += lrelu(qx + bf2f((unsigned short)(kp & 0xffff)));
            ay += lrelu(qy + bf2f((unsigned short)(kp >> 16)));
        }
    }
    unsigned int o = (unsigned int)f2bf(ax) | ((unsigned int)f2bf(ay) << 16);
    *(unsigned int*)(agg + (size_t)node * H + lane * 2) = o;
}

// ---------------- segmented graph pooling (gid sorted): hg[g] = sum rows gstart[g]..gstart[g+1] ----------------
__global__ __launch_bounds__(256) void k_pool_seg(const unsigned short* __restrict__ h,
                                                  const int* __restrict__ gstart,
                                                  float* __restrict__ hg) {
    int g = blockIdx.x * 4 + (threadIdx.x >> 6);
    if (g >= NG) return;
    int lane = threadIdx.x & 63;
    int s = gstart[g], e = gstart[g + 1];
    float ax = 0.f, ay = 0.f;
    for (int n = s; n < e; ++n) {
        unsigned int hp = *(const unsigned int*)(h + (size_t)n * H + lane * 2);
        ax += bflo(hp);
        ay += bfhi(hp);
    }
    float2 o;
    o.x = ax;
    o.y = ay;
    *(float2*)(hg + (size_t)g * H + lane * 2) = o;
}

// ---------------- fused MLP head (two-pass BN, matches reference exactly) ----------------
__global__ __launch_bounds__(1024) void k_head(const float* __restrict__ hg,
                                               const float* __restrict__ W1, const float* __restrict__ b1,
                                               const float* __restrict__ g1, const float* __restrict__ be1,
                                               const float* __restrict__ W2, const float* __restrict__ b2,
                                               const float* __restrict__ g2, const float* __restrict__ be2,
                                               const float* __restrict__ W3, const float* __restrict__ b3,
                                               float* __restrict__ x1, float* __restrict__ x2,
                                               float* __restrict__ out) {
    __shared__ float W1s[128 * 64];
    __shared__ float W2s[64 * 32];
    __shared__ float red[1024];
    __shared__ float stats1[128];
    __shared__ float stats2[64];
    int t = threadIdx.x;
    for (int i = t; i < 128 * 64; i += 1024) W1s[i] = W1[i];
    for (int i = t; i < 64 * 32; i += 1024) W2s[i] = W2[i];
    __syncthreads();

    // phase A: x1 = hg @ W1 + b1   [1000,128]@[128,64]
    for (int idx = t; idx < NG * 64; idx += 1024) {
        int g = idx >> 6, c = idx & 63;
        const float* row = hg + (size_t)g * H;
        float acc = b1[c];
        for (int j = 0; j < 128; ++j) acc += row[j] * W1s[j * 64 + c];
        x1[idx] = acc;
    }
    __syncthreads();

    // phase B: BN1 stats, two-pass (mean, then var)
    {
        int c = t & 63, rc = t >> 6;  // 16 row-chunks
        float s = 0.f;
        for (int g = rc; g < NG; g += 16) s += x1[g * 64 + c];
        red[t] = s;
        __syncthreads();
        if (t < 64) {
            float S = 0.f;
            for (int i = 0; i < 16; ++i) S += red[i * 64 + t];
            stats1[t] = S / NG;
        }
        __syncthreads();
        float mu = stats1[c];
        float s2 = 0.f;
        for (int g = rc; g < NG; g += 16) {
            float d = x1[g * 64 + c] - mu;
            s2 += d * d;
        }
        red[t] = s2;
        __syncthreads();
        if (t < 64) {
            float Q = 0.f;
            for (int i = 0; i < 16; ++i) Q += red[i * 64 + t];
            stats1[64 + t] = rsqrtf(Q / NG + 1e-5f);
        }
        __syncthreads();
    }

    // phase C: apply BN1 + lrelu in-place
    for (int idx = t; idx < NG * 64; idx += 1024) {
        int c = idx & 63;
        float v = (x1[idx] - stats1[c]) * stats1[64 + c] * g1[c] + be1[c];
        x1[idx] = lrelu(v);
    }
    __syncthreads();

    // phase D: x2 = x1 @ W2 + b2   [1000,64]@[64,32]
    for (int idx = t; idx < NG * 32; idx += 1024) {
        int g = idx >> 5, c = idx & 31;
        const float* row = x1 + (size_t)g * 64;
        float acc = b2[c];
        for (int j = 0; j < 64; ++j) acc += row[j] * W2s[j * 32 + c];
        x2[idx] = acc;
    }
    __syncthreads();

    // phase E: BN2 stats, two-pass
    {
        int c = t & 31, rc = t >> 5;  // 32 row-chunks
        float s = 0.f;
        for (int g = rc; g < NG; g += 32) s += x2[g * 32 + c];
        red[t] = s;
        __syncthreads();
        if (t < 32) {
            float S = 0.f;
            for (int i = 0; i < 32; ++i) S += red[i * 32 + t];
            stats2[t] = S / NG;
        }
        __syncthreads();
        float mu = stats2[c];
        float s2 = 0.f;
        for (int g = rc; g < NG; g += 32) {
            float d = x2[g * 32 + c] - mu;
            s2 += d * d;
        }
        red[t] = s2;
        __syncthreads();
        if (t < 32) {
            float Q = 0.f;
            for (int i = 0; i < 32; ++i) Q += red[i * 32 + t];
            stats2[32 + t] = rsqrtf(Q / NG + 1e-5f);
        }
        __syncthreads();
    }

    // phase F: out[g] = lrelu(bn2(x2)) @ W3 + b3
    for (int g = t; g < NG; g += 1024) {
        float acc = b3[0];
        for (int j = 0; j < 32; ++j) {
            float v = (x2[g * 32 + j] - stats2[j]) * stats2[32 + j] * g2[j] + be2[j];
            acc += lrelu(v) * W3[j];
        }
        out[g] = acc;
    }
}

extern "C" void kernel_launch(void* const* d_in, const int* in_sizes, int n_in,
                              void* d_out, int out_size, void* d_ws, size_t ws_size,
                              hipStream_t stream) {
    const int* nfeats = (const int*)d_in[0];
    // d_in[1] = efeats (unused by reference)
    const int* src = (const int*)d_in[2];
    const int* dst = (const int*)d_in[3];
    const int* gid = (const int*)d_in[4];
    const float* emb = (const float*)d_in[5];
    const float* Wq = (const float*)d_in[6];
    const float* bq = (const float*)d_in[7];
    const float* Wk = (const float*)d_in[8];
    const float* bk = (const float*)d_in[9];
    const float* Wr = (const float*)d_in[10];
    const float* br = (const float*)d_in[11];
    const float* W1 = (const float*)d_in[12];
    const float* b1 = (const float*)d_in[13];
    const float* g1 = (const float*)d_in[14];
    const float* be1 = (const float*)d_in[15];
    const float* W2 = (const float*)d_in[16];
    const float* b2 = (const float*)d_in[17];
    const float* g2 = (const float*)d_in[18];
    const float* be2 = (const float*)d_in[19];
    const float* W3 = (const float*)d_in[20];
    const float* b3 = (const float*)d_in[21];
    float* out = (float*)d_out;

    size_t nh = (size_t)NP * H;  // bf16 elements per node buffer
    unsigned short* P0 = (unsigned short*)d_ws;
    unsigned short* P1 = P0 + nh;
    unsigned short* P2 = P1 + nh;
    unsigned short* WT = P2 + nh;                // 12 * 128*128 bf16
    float* hg = (float*)(WT + 12 * H * H);
    float* x1 = hg + (size_t)NG * H;
    float* x2 = x1 + (size_t)NG * 64;
    float* st = x2 + (size_t)NG * 32;
    int* cursor = (int*)(st + 2 * 64);  // NN (also used as deg for histogram)
    int* rowp = cursor + NN;            // NN+1
    int* bsum = rowp + NN + 1;          // 128
    int* csr_src = bsum + 128;          // NE
    int* gstart = csr_src + NE;         // NG+1

    // ---- CSR build (dst-sorted adjacency) + graph boundaries ----
    hipMemsetAsync(cursor, 0, NN * sizeof(int), stream);
    k_hist<<<(NE + 255) / 256, 256, 0, stream>>>(dst, cursor);
    k_scan1<<<SCAN_BLOCKS, 1024, 0, stream>>>(cursor, rowp, bsum);
    k_scan2<<<1, 128, 0, stream>>>(bsum);
    k_scan3<<<(NN + 255) / 256, 256, 0, stream>>>(bsum, rowp, cursor);
    k_scatter<<<(NE + 255) / 256, 256, 0, stream>>>(src, dst, cursor, csr_src);
    k_gbound<<<(NG + 256) / 256, 256, 0, stream>>>(gid, gstart);

    // ---- weight prep + atom encoder ----
    k_wt<<<12, 256, 0, stream>>>(Wq, Wk, Wr, WT);
    k_atom<<<NN / 4, 256, 0, stream>>>(nfeats, emb, P0);

    unsigned short* h = P0;
    unsigned short* q = P1;
    unsigned short* k = P2;
    const int NB = NP / 128;  // 782
    for (int l = 0; l < NLAYER; ++l) {
        k_qk_mfma<<<NB, 256, 0, stream>>>(h, WT + (size_t)(l * 3 + 0) * H * H, bq + l * H,
                                          WT + (size_t)(l * 3 + 1) * H * H, bk + l * H, q, k);
        // h is dead after qk GEMM; reuse it as agg output
        k_agg<<<(NN + 3) / 4, 256, 0, stream>>>(q, k, rowp, csr_src, h);
        k_r_mfma<<<NB, 256, 0, stream>>>(h, WT + (size_t)(l * 3 + 2) * H * H, br + l * H, q);
        unsigned short* newh = q;
        q = k;
        k = h;
        h = newh;
    }

    k_pool_seg<<<(NG + 3) / 4, 256, 0, stream>>>(h, gstart, hg);
    k_head<<<1, 1024, 0, stream>>>(hg, W1, b1, g1, be1, W2, b2, g2, be2, W3, b3, x1, x2, out);
}

// Round 6
// 893.013 us; speedup vs baseline: 2.1300x; 2.1300x over previous
//
#include <hip/hip_runtime.h>

#define NN 100000
#define NP 100096   // padded rows (782 blocks * 128)
#define NE 1000000
#define NG 1000
#define H 128
#define NLAYER 4
#define NEG 0.2f
#define SCAN_BLOCKS 98

using short8 = __attribute__((ext_vector_type(8))) short;
using fx4 = __attribute__((ext_vector_type(4))) float;

__device__ __forceinline__ float lrelu(float x) { return x >= 0.f ? x : NEG * x; }

__device__ __forceinline__ unsigned short f2bf(float f) {
    union { float f; unsigned int u; } v;
    v.f = f;
    return (unsigned short)((v.u + 0x7fffu + ((v.u >> 16) & 1u)) >> 16);
}
__device__ __forceinline__ float bf2f(unsigned short h) {
    union { unsigned int u; float f; } v;
    v.u = ((unsigned int)h) << 16;
    return v.f;
}
__device__ __forceinline__ float bflo(unsigned int u) {
    union { unsigned int x; float f; } v;
    v.x = u << 16;
    return v.f;
}
__device__ __forceinline__ float bfhi(unsigned int u) {
    union { unsigned int x; float f; } v;
    v.x = u & 0xffff0000u;
    return v.f;
}

// ---------------- Atom encoder ----------------
__global__ __launch_bounds__(256) void k_atom(const int* __restrict__ nfeats,
                                              const float* __restrict__ emb,
                                              unsigned short* __restrict__ h) {
    int node = blockIdx.x * 4 + (threadIdx.x >> 6);
    if (node >= NN) return;
    int lane = threadIdx.x & 63;
    int c = lane * 2;
    float ax = 0.f, ay = 0.f;
#pragma unroll
    for (int f = 0; f < 9; ++f) {
        int idx = nfeats[node * 9 + f];
        float2 e = *(const float2*)(emb + (size_t)((f << 6) + idx) * H + c);
        ax += e.x;
        ay += e.y;
    }
    unsigned int packed = (unsigned int)f2bf(ax) | ((unsigned int)f2bf(ay) << 16);
    *(unsigned int*)(h + (size_t)node * H + c) = packed;
}

// ---------------- Weight prep ----------------
__global__ __launch_bounds__(256) void k_wt(const float* __restrict__ Wq,
                                            const float* __restrict__ Wk,
                                            const float* __restrict__ Wr,
                                            unsigned short* __restrict__ WT) {
    int mat = blockIdx.x;
    int l = mat / 3;
    int kind = mat - l * 3;
    const float* src = (kind == 0 ? Wq : kind == 1 ? Wk : Wr) + (size_t)l * H * H;
    unsigned short* dst = WT + (size_t)mat * H * H;
    for (int idx = threadIdx.x; idx < H * H; idx += 256) {
        int kk = idx >> 7, n = idx & 127;
        dst[n * H + kk] = f2bf(src[idx]);
    }
}

// ---------------- CSR build ----------------
__global__ __launch_bounds__(256) void k_hist(const int* __restrict__ dst, int* __restrict__ deg) {
    int i = blockIdx.x * blockDim.x + threadIdx.x;
    if (i < NE) atomicAdd(&deg[dst[i]], 1);
}

__global__ __launch_bounds__(1024) void k_scan1(const int* __restrict__ deg,
                                                int* __restrict__ rowp,
                                                int* __restrict__ bsum) {
    __shared__ int tmp[1024];
    int t = threadIdx.x;
    int i = blockIdx.x * 1024 + t;
    int v = (i < NN) ? deg[i] : 0;
    tmp[t] = v;
    __syncthreads();
    for (int off = 1; off < 1024; off <<= 1) {
        int u = (t >= off) ? tmp[t - off] : 0;
        __syncthreads();
        tmp[t] += u;
        __syncthreads();
    }
    if (i < NN) rowp[i] = tmp[t] - v;
    if (t == 1023) bsum[blockIdx.x] = tmp[1023];
}

__global__ __launch_bounds__(128) void k_scan2(int* __restrict__ bsum) {
    __shared__ int tmp[128];
    int t = threadIdx.x;
    int v = (t < SCAN_BLOCKS) ? bsum[t] : 0;
    tmp[t] = v;
    __syncthreads();
    for (int off = 1; off < 128; off <<= 1) {
        int u = (t >= off) ? tmp[t - off] : 0;
        __syncthreads();
        tmp[t] += u;
        __syncthreads();
    }
    if (t < SCAN_BLOCKS) bsum[t] = tmp[t] - v;
}

__global__ __launch_bounds__(256) void k_scan3(const int* __restrict__ bsum,
                                               int* __restrict__ rowp,
                                               int* __restrict__ cursor) {
    int i = blockIdx.x * blockDim.x + threadIdx.x;
    if (i < NN) {
        int v = rowp[i] + bsum[i >> 10];
        rowp[i] = v;
        cursor[i] = v;
    }
    if (i == 0) rowp[NN] = NE;
}

__global__ __launch_bounds__(256) void k_scatter(const int* __restrict__ src,
                                                 const int* __restrict__ dst,
                                                 int* __restrict__ cursor,
                                                 int* __restrict__ csr_src) {
    int i = blockIdx.x * blockDim.x + threadIdx.x;
    if (i < NE) {
        int pos = atomicAdd(&cursor[dst[i]], 1);
        csr_src[pos] = src[i];
    }
}

// ---------------- graph boundaries ----------------
__global__ __launch_bounds__(256) void k_gbound(const int* __restrict__ gid,
                                                int* __restrict__ gstart) {
    int g = blockIdx.x * blockDim.x + threadIdx.x;
    if (g > NG) return;
    if (g == NG) { gstart[NG] = NN; return; }
    int lo = 0, hi = NN;
    while (lo < hi) {
        int mid = (lo + hi) >> 1;
        if (gid[mid] < g) lo = mid + 1; else hi = mid;
    }
    gstart[g] = lo;
}

// ---------------- fused q/k GEMM via MFMA ----------------
__global__ __launch_bounds__(256) void k_qk_mfma(const unsigned short* __restrict__ h,
                                                 const unsigned short* __restrict__ WTq,
                                                 const float* __restrict__ bq,
                                                 const unsigned short* __restrict__ WTk,
                                                 const float* __restrict__ bk,
                                                 unsigned short* __restrict__ q,
                                                 unsigned short* __restrict__ k) {
    int lane = threadIdx.x & 63;
    int wave = threadIdx.x >> 6;
    int row0 = blockIdx.x * 128 + wave * 32;
    int lrow = lane & 15;
    int lk = (lane >> 4) << 3;

    short8 a[2][4];
#pragma unroll
    for (int rt = 0; rt < 2; ++rt)
#pragma unroll
        for (int ks = 0; ks < 4; ++ks)
            a[rt][ks] = *(const short8*)(h + (size_t)(row0 + rt * 16 + lrow) * H + ks * 32 + lk);

    fx4 aq[2][8], ak[2][8];
#pragma unroll
    for (int ct = 0; ct < 8; ++ct) {
        float vq = bq[ct * 16 + lrow];
        float vk = bk[ct * 16 + lrow];
#pragma unroll
        for (int rt = 0; rt < 2; ++rt) {
            aq[rt][ct] = fx4{vq, vq, vq, vq};
            ak[rt][ct] = fx4{vk, vk, vk, vk};
        }
    }

#pragma unroll
    for (int ks = 0; ks < 4; ++ks)
#pragma unroll
        for (int ct = 0; ct < 8; ++ct) {
            short8 wq = *(const short8*)(WTq + (ct * 16 + lrow) * H + ks * 32 + lk);
            short8 wk = *(const short8*)(WTk + (ct * 16 + lrow) * H + ks * 32 + lk);
#pragma unroll
            for (int rt = 0; rt < 2; ++rt) {
                aq[rt][ct] = __builtin_amdgcn_mfma_f32_16x16x32_bf16(a[rt][ks], wq, aq[rt][ct], 0, 0, 0);
                ak[rt][ct] = __builtin_amdgcn_mfma_f32_16x16x32_bf16(a[rt][ks], wk, ak[rt][ct], 0, 0, 0);
            }
        }

#pragma unroll
    for (int rt = 0; rt < 2; ++rt)
#pragma unroll
        for (int ct = 0; ct < 8; ++ct)
#pragma unroll
            for (int rg = 0; rg < 4; ++rg) {
                int r = row0 + rt * 16 + ((lane >> 4) << 2) + rg;
                if (r < NN) {
                    q[(size_t)r * H + ct * 16 + lrow] = f2bf(aq[rt][ct][rg]);
                    k[(size_t)r * H + ct * 16 + lrow] = f2bf(ak[rt][ct][rg]);
                }
            }
}

// ---------------- h_new = lrelu(agg@Wr + br) via MFMA ----------------
__global__ __launch_bounds__(256) void k_r_mfma(const unsigned short* __restrict__ agg,
                                                const unsigned short* __restrict__ WTr,
                                                const float* __restrict__ br,
                                                unsigned short* __restrict__ hout) {
    int lane = threadIdx.x & 63;
    int wave = threadIdx.x >> 6;
    int row0 = blockIdx.x * 128 + wave * 32;
    int lrow = lane & 15;
    int lk = (lane >> 4) << 3;

    short8 a[2][4];
#pragma unroll
    for (int rt = 0; rt < 2; ++rt)
#pragma unroll
        for (int ks = 0; ks < 4; ++ks)
            a[rt][ks] = *(const short8*)(agg + (size_t)(row0 + rt * 16 + lrow) * H + ks * 32 + lk);

    fx4 acc[2][8];
#pragma unroll
    for (int ct = 0; ct < 8; ++ct) {
        float v = br[ct * 16 + lrow];
#pragma unroll
        for (int rt = 0; rt < 2; ++rt) acc[rt][ct] = fx4{v, v, v, v};
    }

#pragma unroll
    for (int ks = 0; ks < 4; ++ks)
#pragma unroll
        for (int ct = 0; ct < 8; ++ct) {
            short8 w = *(const short8*)(WTr + (ct * 16 + lrow) * H + ks * 32 + lk);
#pragma unroll
            for (int rt = 0; rt < 2; ++rt)
                acc[rt][ct] = __builtin_amdgcn_mfma_f32_16x16x32_bf16(a[rt][ks], w, acc[rt][ct], 0, 0, 0);
        }

#pragma unroll
    for (int rt = 0; rt < 2; ++rt)
#pragma unroll
        for (int ct = 0; ct < 8; ++ct)
#pragma unroll
            for (int rg = 0; rg < 4; ++rg) {
                int r = row0 + rt * 16 + ((lane >> 4) << 2) + rg;
                if (r < NN)
                    hout[(size_t)r * H + ct * 16 + lrow] = f2bf(lrelu(acc[rt][ct][rg]));
            }
}

// ---------------- aggregation (gather, round-3 proven) ----------------
__global__ __launch_bounds__(256) void k_agg(const unsigned short* __restrict__ q,
                                             const unsigned short* __restrict__ kk,
                                             const int* __restrict__ rowp,
                                             const int* __restrict__ csr_src,
                                             unsigned short* __restrict__ agg) {
    int node = blockIdx.x * 4 + (threadIdx.x >> 6);
    if (node >= NN) return;
    int lane = threadIdx.x & 63;
    int start = rowp[node];
    int end = rowp[node + 1];
    unsigned int qp = *(const unsigned int*)(q + (size_t)node * H + lane * 2);
    float qx = bf2f((unsigned short)(qp & 0xffff));
    float qy = bf2f((unsigned short)(qp >> 16));
    float ax = 0.f, ay = 0.f;
    for (int base = start; base < end; base += 64) {
        int cnt = end - base;
        if (cnt > 64) cnt = 64;
        int sid = (lane < cnt) ? csr_src[base + lane] : 0;
        for (int j = 0; j < cnt; ++j) {
            int s = __shfl(sid, j);
            unsigned int kp = *(const unsigned int*)(kk + (size_t)s * H + lane * 2);
            ax += lrelu(qx + bf2f((unsigned short)(kp & 0xffff)));
            ay += lrelu(qy + bf2f((unsigned short)(kp >> 16)));
        }
    }
    unsigned int o = (unsigned int)f2bf(ax) | ((unsigned int)f2bf(ay) << 16);
    *(unsigned int*)(agg + (size_t)node * H + lane * 2) = o;
}

// ---------------- segmented graph pooling ----------------
__global__ __launch_bounds__(256) void k_pool_seg(const unsigned short* __restrict__ h,
                                                  const int* __restrict__ gstart,
                                                  float* __restrict__ hg) {
    int g = blockIdx.x * 4 + (threadIdx.x >> 6);
    if (g >= NG) return;
    int lane = threadIdx.x & 63;
    int s = gstart[g], e = gstart[g + 1];
    float ax = 0.f, ay = 0.f;
    for (int n = s; n < e; ++n) {
        unsigned int hp = *(const unsigned int*)(h + (size_t)n * H + lane * 2);
        ax += bflo(hp);
        ay += bfhi(hp);
    }
    float2 o;
    o.x = ax;
    o.y = ay;
    *(float2*)(hg + (size_t)g * H + lane * 2) = o;
}

// ---------------- MLP head: multi-block kernels ----------------
// x1 = hg @ W1 + b1   [1000,128]@[128,64]; 4 graphs/block, W1 in LDS
__global__ __launch_bounds__(256) void k_mlp1(const float* __restrict__ hg,
                                              const float* __restrict__ W1,
                                              const float* __restrict__ b1,
                                              float* __restrict__ x1) {
    __shared__ float W1s[128 * 64];
    __shared__ float hgs[4 * 128];
    int t = threadIdx.x;
    int g0 = blockIdx.x * 4;
#pragma unroll
    for (int i = 0; i < 32; ++i) W1s[t + i * 256] = W1[t + i * 256];
    for (int i = t; i < 4 * 128; i += 256) hgs[i] = hg[(size_t)g0 * H + i];
    __syncthreads();
    int g = t >> 6, c = t & 63;
    float acc = b1[c];
    const float* row = hgs + g * 128;
    for (int j = 0; j < 128; ++j) acc += row[j] * W1s[j * 64 + c];
    x1[(g0 + g) * 64 + c] = acc;
}

// two-pass BN stats over [NG, C]; single 1024-thread block
template <int C>
__global__ __launch_bounds__(1024) void k_bnstats(const float* __restrict__ x,
                                                  float* __restrict__ stats) {
    __shared__ float red[1024];
    __shared__ float mus[C];
    int t = threadIdx.x;
    int c = t & (C - 1), rc = t / C;
    const int R = 1024 / C;
    float s = 0.f;
    for (int g = rc; g < NG; g += R) s += x[g * C + c];
    red[t] = s;
    __syncthreads();
    if (t < C) {
        float S = 0.f;
        for (int i = 0; i < R; ++i) S += red[i * C + t];
        float mu = S / NG;
        mus[t] = mu;
        stats[t] = mu;
    }
    __syncthreads();
    float mu = mus[c];
    float s2 = 0.f;
    for (int g = rc; g < NG; g += R) {
        float d = x[g * C + c] - mu;
        s2 += d * d;
    }
    red[t] = s2;
    __syncthreads();
    if (t < C) {
        float Q = 0.f;
        for (int i = 0; i < R; ++i) Q += red[i * C + t];
        stats[C + t] = rsqrtf(Q / NG + 1e-5f);
    }
}

// x2 = lrelu(bn1(x1)) @ W2 + b2   [1000,64]@[64,32]; 8 graphs/block
__global__ __launch_bounds__(256) void k_mlp2f(const float* __restrict__ x1,
                                               const float* __restrict__ st,
                                               const float* __restrict__ g1,
                                               const float* __restrict__ be1,
                                               const float* __restrict__ W2,
                                               const float* __restrict__ b2,
                                               float* __restrict__ x2) {
    __shared__ float W2s[64 * 32];
    __shared__ float x1s[8 * 64];
    int t = threadIdx.x;
    int g0 = blockIdx.x * 8;
#pragma unroll
    for (int i = 0; i < 8; ++i) W2s[t + i * 256] = W2[t + i * 256];
#pragma unroll
    for (int i = 0; i < 2; ++i) {
        int idx = t + i * 256;
        int c = idx & 63;
        float v = x1[(size_t)g0 * 64 + idx];
        v = (v - st[c]) * st[64 + c] * g1[c] + be1[c];
        x1s[idx] = lrelu(v);
    }
    __syncthreads();
    int g = t >> 5, c = t & 31;
    float acc = b2[c];
    const float* row = x1s + g * 64;
    for (int j = 0; j < 64; ++j) acc += row[j] * W2s[j * 32 + c];
    x2[(g0 + g) * 32 + c] = acc;
}

// out = lrelu(bn2(x2)) @ W3 + b3; one thread per graph
__global__ __launch_bounds__(256) void k_mlp3f(const float* __restrict__ x2,
                                               const float* __restrict__ st,
                                               const float* __restrict__ g2,
                                               const float* __restrict__ be2,
                                               const float* __restrict__ W3,
                                               const float* __restrict__ b3,
                                               float* __restrict__ out) {
    int g = blockIdx.x * blockDim.x + threadIdx.x;
    if (g >= NG) return;
    float acc = b3[0];
    for (int j = 0; j < 32; ++j) {
        float v = (x2[g * 32 + j] - st[j]) * st[32 + j] * g2[j] + be2[j];
        acc += lrelu(v) * W3[j];
    }
    out[g] = acc;
}

extern "C" void kernel_launch(void* const* d_in, const int* in_sizes, int n_in,
                              void* d_out, int out_size, void* d_ws, size_t ws_size,
                              hipStream_t stream) {
    const int* nfeats = (const int*)d_in[0];
    const int* src = (const int*)d_in[2];
    const int* dst = (const int*)d_in[3];
    const int* gid = (const int*)d_in[4];
    const float* emb = (const float*)d_in[5];
    const float* Wq = (const float*)d_in[6];
    const float* bq = (const float*)d_in[7];
    const float* Wk = (const float*)d_in[8];
    const float* bk = (const float*)d_in[9];
    const float* Wr = (const float*)d_in[10];
    const float* br = (const float*)d_in[11];
    const float* W1 = (const float*)d_in[12];
    const float* b1 = (const float*)d_in[13];
    const float* g1 = (const float*)d_in[14];
    const float* be1 = (const float*)d_in[15];
    const float* W2 = (const float*)d_in[16];
    const float* b2 = (const float*)d_in[17];
    const float* g2 = (const float*)d_in[18];
    const float* be2 = (const float*)d_in[19];
    const float* W3 = (const float*)d_in[20];
    const float* b3 = (const float*)d_in[21];
    float* out = (float*)d_out;

    size_t nh = (size_t)NP * H;
    unsigned short* P0 = (unsigned short*)d_ws;
    unsigned short* P1 = P0 + nh;
    unsigned short* P2 = P1 + nh;
    unsigned short* WT = P2 + nh;
    float* hg = (float*)(WT + 12 * H * H);
    float* x1 = hg + (size_t)NG * H;
    float* x2 = x1 + (size_t)NG * 64;
    float* st = x2 + (size_t)NG * 32;
    int* cursor = (int*)(st + 2 * 64);
    int* rowp = cursor + NN;
    int* bsum = rowp + NN + 1;
    int* csr_src = bsum + 128;
    int* gstart = csr_src + NE;

    // ---- CSR build + graph boundaries ----
    hipMemsetAsync(cursor, 0, NN * sizeof(int), stream);
    k_hist<<<(NE + 255) / 256, 256, 0, stream>>>(dst, cursor);
    k_scan1<<<SCAN_BLOCKS, 1024, 0, stream>>>(cursor, rowp, bsum);
    k_scan2<<<1, 128, 0, stream>>>(bsum);
    k_scan3<<<(NN + 255) / 256, 256, 0, stream>>>(bsum, rowp, cursor);
    k_scatter<<<(NE + 255) / 256, 256, 0, stream>>>(src, dst, cursor, csr_src);
    k_gbound<<<(NG + 256) / 256, 256, 0, stream>>>(gid, gstart);

    // ---- weight prep + atom encoder ----
    k_wt<<<12, 256, 0, stream>>>(Wq, Wk, Wr, WT);
    k_atom<<<NN / 4, 256, 0, stream>>>(nfeats, emb, P0);

    unsigned short* h = P0;
    unsigned short* q = P1;
    unsigned short* k = P2;
    const int NB = NP / 128;
    for (int l = 0; l < NLAYER; ++l) {
        k_qk_mfma<<<NB, 256, 0, stream>>>(h, WT + (size_t)(l * 3 + 0) * H * H, bq + l * H,
                                          WT + (size_t)(l * 3 + 1) * H * H, bk + l * H, q, k);
        k_agg<<<(NN + 3) / 4, 256, 0, stream>>>(q, k, rowp, csr_src, h);
        k_r_mfma<<<NB, 256, 0, stream>>>(h, WT + (size_t)(l * 3 + 2) * H * H, br + l * H, q);
        unsigned short* newh = q;
        q = k;
        k = h;
        h = newh;
    }

    k_pool_seg<<<(NG + 3) / 4, 256, 0, stream>>>(h, gstart, hg);

    // ---- MLP head (multi-block, BN via tiny single-block stats kernels) ----
    k_mlp1<<<NG / 4, 256, 0, stream>>>(hg, W1, b1, x1);
    k_bnstats<64><<<1, 1024, 0, stream>>>(x1, st);
    k_mlp2f<<<NG / 8, 256, 0, stream>>>(x1, st, g1, be1, W2, b2, x2);
    k_bnstats<32><<<1, 1024, 0, stream>>>(x2, st);
    k_mlp3f<<<(NG + 255) / 256, 256, 0, stream>>>(x2, st, g2, be2, W3, b3, out);
}

// Round 7
// 752.826 us; speedup vs baseline: 2.5267x; 1.1862x over previous
//
#include <hip/hip_runtime.h>

#define NN 100000
#define NP 100096   // padded rows (782 blocks * 128)
#define NE 1000000
#define NG 1000
#define H 128
#define NLAYER 4
#define NEG 0.2f
#define SCAN_BLOCKS 98

using short8 = __attribute__((ext_vector_type(8))) short;
using fx4 = __attribute__((ext_vector_type(4))) float;

__device__ __forceinline__ float lrelu(float x) { return x >= 0.f ? x : NEG * x; }

__device__ __forceinline__ unsigned short f2bf(float f) {
    union { float f; unsigned int u; } v;
    v.f = f;
    return (unsigned short)((v.u + 0x7fffu + ((v.u >> 16) & 1u)) >> 16);
}
__device__ __forceinline__ float bf2f(unsigned short h) {
    union { unsigned int u; float f; } v;
    v.u = ((unsigned int)h) << 16;
    return v.f;
}
__device__ __forceinline__ float bflo(unsigned int u) {
    union { unsigned int x; float f; } v;
    v.x = u << 16;
    return v.f;
}
__device__ __forceinline__ float bfhi(unsigned int u) {
    union { unsigned int x; float f; } v;
    v.x = u & 0xffff0000u;
    return v.f;
}

// ---------------- Atom encoder ----------------
__global__ __launch_bounds__(256) void k_atom(const int* __restrict__ nfeats,
                                              const float* __restrict__ emb,
                                              unsigned short* __restrict__ h) {
    int node = blockIdx.x * 4 + (threadIdx.x >> 6);
    if (node >= NN) return;
    int lane = threadIdx.x & 63;
    int c = lane * 2;
    float ax = 0.f, ay = 0.f;
#pragma unroll
    for (int f = 0; f < 9; ++f) {
        int idx = nfeats[node * 9 + f];
        float2 e = *(const float2*)(emb + (size_t)((f << 6) + idx) * H + c);
        ax += e.x;
        ay += e.y;
    }
    unsigned int packed = (unsigned int)f2bf(ax) | ((unsigned int)f2bf(ay) << 16);
    *(unsigned int*)(h + (size_t)node * H + c) = packed;
}

// ---------------- Weight prep ----------------
__global__ __launch_bounds__(256) void k_wt(const float* __restrict__ Wq,
                                            const float* __restrict__ Wk,
                                            const float* __restrict__ Wr,
                                            unsigned short* __restrict__ WT) {
    int mat = blockIdx.x;
    int l = mat / 3;
    int kind = mat - l * 3;
    const float* src = (kind == 0 ? Wq : kind == 1 ? Wk : Wr) + (size_t)l * H * H;
    unsigned short* dst = WT + (size_t)mat * H * H;
    for (int idx = threadIdx.x; idx < H * H; idx += 256) {
        int kk = idx >> 7, n = idx & 127;
        dst[n * H + kk] = f2bf(src[idx]);
    }
}

// ---------------- CSR build ----------------
__global__ __launch_bounds__(256) void k_hist(const int* __restrict__ dst, int* __restrict__ deg) {
    int i = blockIdx.x * blockDim.x + threadIdx.x;
    if (i < NE) atomicAdd(&deg[dst[i]], 1);
}

__global__ __launch_bounds__(1024) void k_scan1(const int* __restrict__ deg,
                                                int* __restrict__ rowp,
                                                int* __restrict__ bsum) {
    __shared__ int tmp[1024];
    int t = threadIdx.x;
    int i = blockIdx.x * 1024 + t;
    int v = (i < NN) ? deg[i] : 0;
    tmp[t] = v;
    __syncthreads();
    for (int off = 1; off < 1024; off <<= 1) {
        int u = (t >= off) ? tmp[t - off] : 0;
        __syncthreads();
        tmp[t] += u;
        __syncthreads();
    }
    if (i < NN) rowp[i] = tmp[t] - v;
    if (t == 1023) bsum[blockIdx.x] = tmp[1023];
}

__global__ __launch_bounds__(128) void k_scan2(int* __restrict__ bsum) {
    __shared__ int tmp[128];
    int t = threadIdx.x;
    int v = (t < SCAN_BLOCKS) ? bsum[t] : 0;
    tmp[t] = v;
    __syncthreads();
    for (int off = 1; off < 128; off <<= 1) {
        int u = (t >= off) ? tmp[t - off] : 0;
        __syncthreads();
        tmp[t] += u;
        __syncthreads();
    }
    if (t < SCAN_BLOCKS) bsum[t] = tmp[t] - v;
}

__global__ __launch_bounds__(256) void k_scan3(const int* __restrict__ bsum,
                                               int* __restrict__ rowp,
                                               int* __restrict__ cursor) {
    int i = blockIdx.x * blockDim.x + threadIdx.x;
    if (i < NN) {
        int v = rowp[i] + bsum[i >> 10];
        rowp[i] = v;
        cursor[i] = v;
    }
    if (i == 0) rowp[NN] = NE;
}

__global__ __launch_bounds__(256) void k_scatter(const int* __restrict__ src,
                                                 const int* __restrict__ dst,
                                                 int* __restrict__ cursor,
                                                 int* __restrict__ csr_src) {
    int i = blockIdx.x * blockDim.x + threadIdx.x;
    if (i < NE) {
        int pos = atomicAdd(&cursor[dst[i]], 1);
        csr_src[pos] = src[i];
    }
}

// ---------------- graph boundaries ----------------
__global__ __launch_bounds__(256) void k_gbound(const int* __restrict__ gid,
                                                int* __restrict__ gstart) {
    int g = blockIdx.x * blockDim.x + threadIdx.x;
    if (g > NG) return;
    if (g == NG) { gstart[NG] = NN; return; }
    int lo = 0, hi = NN;
    while (lo < hi) {
        int mid = (lo + hi) >> 1;
        if (gid[mid] < g) lo = mid + 1; else hi = mid;
    }
    gstart[g] = lo;
}

// ---------------- fused q/k GEMM via MFMA (layer 0 entry) ----------------
__global__ __launch_bounds__(256) void k_qk_mfma(const unsigned short* __restrict__ h,
                                                 const unsigned short* __restrict__ WTq,
                                                 const float* __restrict__ bq,
                                                 const unsigned short* __restrict__ WTk,
                                                 const float* __restrict__ bk,
                                                 unsigned short* __restrict__ q,
                                                 unsigned short* __restrict__ k) {
    int lane = threadIdx.x & 63;
    int wave = threadIdx.x >> 6;
    int row0 = blockIdx.x * 128 + wave * 32;
    int lrow = lane & 15;
    int lk = (lane >> 4) << 3;

    short8 a[2][4];
#pragma unroll
    for (int rt = 0; rt < 2; ++rt)
#pragma unroll
        for (int ks = 0; ks < 4; ++ks)
            a[rt][ks] = *(const short8*)(h + (size_t)(row0 + rt * 16 + lrow) * H + ks * 32 + lk);

    fx4 aq[2][8], ak[2][8];
#pragma unroll
    for (int ct = 0; ct < 8; ++ct) {
        float vq = bq[ct * 16 + lrow];
        float vk = bk[ct * 16 + lrow];
#pragma unroll
        for (int rt = 0; rt < 2; ++rt) {
            aq[rt][ct] = fx4{vq, vq, vq, vq};
            ak[rt][ct] = fx4{vk, vk, vk, vk};
        }
    }

#pragma unroll
    for (int ks = 0; ks < 4; ++ks)
#pragma unroll
        for (int ct = 0; ct < 8; ++ct) {
            short8 wq = *(const short8*)(WTq + (ct * 16 + lrow) * H + ks * 32 + lk);
            short8 wk = *(const short8*)(WTk + (ct * 16 + lrow) * H + ks * 32 + lk);
#pragma unroll
            for (int rt = 0; rt < 2; ++rt) {
                aq[rt][ct] = __builtin_amdgcn_mfma_f32_16x16x32_bf16(a[rt][ks], wq, aq[rt][ct], 0, 0, 0);
                ak[rt][ct] = __builtin_amdgcn_mfma_f32_16x16x32_bf16(a[rt][ks], wk, ak[rt][ct], 0, 0, 0);
            }
        }

#pragma unroll
    for (int rt = 0; rt < 2; ++rt)
#pragma unroll
        for (int ct = 0; ct < 8; ++ct)
#pragma unroll
            for (int rg = 0; rg < 4; ++rg) {
                int r = row0 + rt * 16 + ((lane >> 4) << 2) + rg;
                if (r < NN) {
                    q[(size_t)r * H + ct * 16 + lrow] = f2bf(aq[rt][ct][rg]);
                    k[(size_t)r * H + ct * 16 + lrow] = f2bf(ak[rt][ct][rg]);
                }
            }
}

// ---------------- h_new = lrelu(agg@Wr + br) via MFMA (final layer) ----------------
__global__ __launch_bounds__(256) void k_r_mfma(const unsigned short* __restrict__ agg,
                                                const unsigned short* __restrict__ WTr,
                                                const float* __restrict__ br,
                                                unsigned short* __restrict__ hout) {
    int lane = threadIdx.x & 63;
    int wave = threadIdx.x >> 6;
    int row0 = blockIdx.x * 128 + wave * 32;
    int lrow = lane & 15;
    int lk = (lane >> 4) << 3;

    short8 a[2][4];
#pragma unroll
    for (int rt = 0; rt < 2; ++rt)
#pragma unroll
        for (int ks = 0; ks < 4; ++ks)
            a[rt][ks] = *(const short8*)(agg + (size_t)(row0 + rt * 16 + lrow) * H + ks * 32 + lk);

    fx4 acc[2][8];
#pragma unroll
    for (int ct = 0; ct < 8; ++ct) {
        float v = br[ct * 16 + lrow];
#pragma unroll
        for (int rt = 0; rt < 2; ++rt) acc[rt][ct] = fx4{v, v, v, v};
    }

#pragma unroll
    for (int ks = 0; ks < 4; ++ks)
#pragma unroll
        for (int ct = 0; ct < 8; ++ct) {
            short8 w = *(const short8*)(WTr + (ct * 16 + lrow) * H + ks * 32 + lk);
#pragma unroll
            for (int rt = 0; rt < 2; ++rt)
                acc[rt][ct] = __builtin_amdgcn_mfma_f32_16x16x32_bf16(a[rt][ks], w, acc[rt][ct], 0, 0, 0);
        }

#pragma unroll
    for (int rt = 0; rt < 2; ++rt)
#pragma unroll
        for (int ct = 0; ct < 8; ++ct)
#pragma unroll
            for (int rg = 0; rg < 4; ++rg) {
                int r = row0 + rt * 16 + ((lane >> 4) << 2) + rg;
                if (r < NN)
                    hout[(size_t)r * H + ct * 16 + lrow] = f2bf(lrelu(acc[rt][ct][rg]));
            }
}

// ---------------- FUSED: h_new = lrelu(agg@Wr+br); q = h_new@Wq+bq; k = h_new@Wk+bk ----------------
// h_new never touches HBM: C-fragments -> wave-private padded LDS slice -> A-fragments.
__global__ __launch_bounds__(256) void k_rqk_mfma(const unsigned short* __restrict__ agg,
                                                  const unsigned short* __restrict__ WTr,
                                                  const float* __restrict__ br,
                                                  const unsigned short* __restrict__ WTq,
                                                  const float* __restrict__ bq,
                                                  const unsigned short* __restrict__ WTk,
                                                  const float* __restrict__ bk,
                                                  unsigned short* __restrict__ q,
                                                  unsigned short* __restrict__ k) {
    __shared__ unsigned short hls[4][32][136];  // 272B row stride: 16B-aligned, ~2-way banks
    int lane = threadIdx.x & 63;
    int wave = threadIdx.x >> 6;
    int row0 = blockIdx.x * 128 + wave * 32;
    int lrow = lane & 15;
    int lk = (lane >> 4) << 3;

    // ---- stage 1: h_new = lrelu(agg @ Wr + br) ----
    short8 a[2][4];
#pragma unroll
    for (int rt = 0; rt < 2; ++rt)
#pragma unroll
        for (int ks = 0; ks < 4; ++ks)
            a[rt][ks] = *(const short8*)(agg + (size_t)(row0 + rt * 16 + lrow) * H + ks * 32 + lk);

    fx4 acc[2][8];
#pragma unroll
    for (int ct = 0; ct < 8; ++ct) {
        float v = br[ct * 16 + lrow];
#pragma unroll
        for (int rt = 0; rt < 2; ++rt) acc[rt][ct] = fx4{v, v, v, v};
    }

#pragma unroll
    for (int ks = 0; ks < 4; ++ks)
#pragma unroll
        for (int ct = 0; ct < 8; ++ct) {
            short8 w = *(const short8*)(WTr + (ct * 16 + lrow) * H + ks * 32 + lk);
#pragma unroll
            for (int rt = 0; rt < 2; ++rt)
                acc[rt][ct] = __builtin_amdgcn_mfma_f32_16x16x32_bf16(a[rt][ks], w, acc[rt][ct], 0, 0, 0);
        }

    // C-layout -> LDS (wave-private slice; no barrier needed, compiler orders ds_write/ds_read)
#pragma unroll
    for (int rt = 0; rt < 2; ++rt)
#pragma unroll
        for (int ct = 0; ct < 8; ++ct)
#pragma unroll
            for (int rg = 0; rg < 4; ++rg) {
                int lr = rt * 16 + ((lane >> 4) << 2) + rg;
                hls[wave][lr][ct * 16 + lrow] = f2bf(lrelu(acc[rt][ct][rg]));
            }

    // ---- stage 2: A-fragments of h_new from LDS; q/k GEMM ----
    short8 a2[2][4];
#pragma unroll
    for (int rt = 0; rt < 2; ++rt)
#pragma unroll
        for (int ks = 0; ks < 4; ++ks)
            a2[rt][ks] = *(const short8*)&hls[wave][rt * 16 + lrow][ks * 32 + lk];

    fx4 aq[2][8], ak[2][8];
#pragma unroll
    for (int ct = 0; ct < 8; ++ct) {
        float vq = bq[ct * 16 + lrow];
        float vk = bk[ct * 16 + lrow];
#pragma unroll
        for (int rt = 0; rt < 2; ++rt) {
            aq[rt][ct] = fx4{vq, vq, vq, vq};
            ak[rt][ct] = fx4{vk, vk, vk, vk};
        }
    }

#pragma unroll
    for (int ks = 0; ks < 4; ++ks)
#pragma unroll
        for (int ct = 0; ct < 8; ++ct) {
            short8 wq = *(const short8*)(WTq + (ct * 16 + lrow) * H + ks * 32 + lk);
            short8 wk = *(const short8*)(WTk + (ct * 16 + lrow) * H + ks * 32 + lk);
#pragma unroll
            for (int rt = 0; rt < 2; ++rt) {
                aq[rt][ct] = __builtin_amdgcn_mfma_f32_16x16x32_bf16(a2[rt][ks], wq, aq[rt][ct], 0, 0, 0);
                ak[rt][ct] = __builtin_amdgcn_mfma_f32_16x16x32_bf16(a2[rt][ks], wk, ak[rt][ct], 0, 0, 0);
            }
        }

#pragma unroll
    for (int rt = 0; rt < 2; ++rt)
#pragma unroll
        for (int ct = 0; ct < 8; ++ct)
#pragma unroll
            for (int rg = 0; rg < 4; ++rg) {
                int r = row0 + rt * 16 + ((lane >> 4) << 2) + rg;
                if (r < NN) {
                    q[(size_t)r * H + ct * 16 + lrow] = f2bf(aq[rt][ct][rg]);
                    k[(size_t)r * H + ct * 16 + lrow] = f2bf(ak[rt][ct][rg]);
                }
            }
}

// ---------------- aggregation: 4 edges/wave/iter, 16 lanes x 16B per edge ----------------
// All __shfl are wave-uniform (whole wave owns one node; loop bounds uniform; jj<=63 always).
__global__ __launch_bounds__(256) void k_agg(const unsigned short* __restrict__ q,
                                             const unsigned short* __restrict__ kk,
                                             const int* __restrict__ rowp,
                                             const int* __restrict__ csr_src,
                                             unsigned short* __restrict__ agg) {
    int node = blockIdx.x * 4 + (threadIdx.x >> 6);
    if (node >= NN) return;
    int lane = threadIdx.x & 63;
    int qt = lane >> 4;   // which edge of the 4-pack
    int ql = lane & 15;   // 16 lanes cover one 256B row, 8 channels each
    int start = rowp[node];
    int end = rowp[node + 1];

    uint4 qp = *(const uint4*)(q + (size_t)node * H + ql * 8);
    float qv0 = bflo(qp.x), qv1 = bfhi(qp.x), qv2 = bflo(qp.y), qv3 = bfhi(qp.y);
    float qv4 = bflo(qp.z), qv5 = bfhi(qp.z), qv6 = bflo(qp.w), qv7 = bfhi(qp.w);
    float a0 = 0.f, a1 = 0.f, a2 = 0.f, a3 = 0.f, a4 = 0.f, a5 = 0.f, a6 = 0.f, a7 = 0.f;

    for (int base = start; base < end; base += 64) {
        int cnt = end - base;
        if (cnt > 64) cnt = 64;
        int sid = (lane < cnt) ? csr_src[base + lane] : 0;  // lanes >= cnt: valid dummy row 0
        int cnt4 = (cnt + 3) & ~3;
        for (int j = 0; j < cnt4; j += 4) {
            int jj = j + qt;               // <= 63 always
            int s = __shfl(sid, jj);       // wave-uniform execution
            uint4 kp = *(const uint4*)(kk + (size_t)s * H + ql * 8);
            if (jj < cnt) {
                a0 += lrelu(qv0 + bflo(kp.x));
                a1 += lrelu(qv1 + bfhi(kp.x));
                a2 += lrelu(qv2 + bflo(kp.y));
                a3 += lrelu(qv3 + bfhi(kp.y));
                a4 += lrelu(qv4 + bflo(kp.z));
                a5 += lrelu(qv5 + bfhi(kp.z));
                a6 += lrelu(qv6 + bflo(kp.w));
                a7 += lrelu(qv7 + bfhi(kp.w));
            }
        }
    }
    // sum the 4 edge-groups (qt 0..3) -> every lane holds full sums
    a0 += __shfl_xor(a0, 16); a0 += __shfl_xor(a0, 32);
    a1 += __shfl_xor(a1, 16); a1 += __shfl_xor(a1, 32);
    a2 += __shfl_xor(a2, 16); a2 += __shfl_xor(a2, 32);
    a3 += __shfl_xor(a3, 16); a3 += __shfl_xor(a3, 32);
    a4 += __shfl_xor(a4, 16); a4 += __shfl_xor(a4, 32);
    a5 += __shfl_xor(a5, 16); a5 += __shfl_xor(a5, 32);
    a6 += __shfl_xor(a6, 16); a6 += __shfl_xor(a6, 32);
    a7 += __shfl_xor(a7, 16); a7 += __shfl_xor(a7, 32);
    if (qt == 0) {
        uint4 o;
        o.x = (unsigned int)f2bf(a0) | ((unsigned int)f2bf(a1) << 16);
        o.y = (unsigned int)f2bf(a2) | ((unsigned int)f2bf(a3) << 16);
        o.z = (unsigned int)f2bf(a4) | ((unsigned int)f2bf(a5) << 16);
        o.w = (unsigned int)f2bf(a6) | ((unsigned int)f2bf(a7) << 16);
        *(uint4*)(agg + (size_t)node * H + ql * 8) = o;
    }
}

// ---------------- segmented graph pooling ----------------
__global__ __launch_bounds__(256) void k_pool_seg(const unsigned short* __restrict__ h,
                                                  const int* __restrict__ gstart,
                                                  float* __restrict__ hg) {
    int g = blockIdx.x * 4 + (threadIdx.x >> 6);
    if (g >= NG) return;
    int lane = threadIdx.x & 63;
    int s = gstart[g], e = gstart[g + 1];
    float ax = 0.f, ay = 0.f;
    for (int n = s; n < e; ++n) {
        unsigned int hp = *(const unsigned int*)(h + (size_t)n * H + lane * 2);
        ax += bflo(hp);
        ay += bfhi(hp);
    }
    float2 o;
    o.x = ax;
    o.y = ay;
    *(float2*)(hg + (size_t)g * H + lane * 2) = o;
}

// ---------------- MLP head ----------------
__global__ __launch_bounds__(256) void k_mlp1(const float* __restrict__ hg,
                                              const float* __restrict__ W1,
                                              const float* __restrict__ b1,
                                              float* __restrict__ x1) {
    __shared__ float W1s[128 * 64];
    __shared__ float hgs[4 * 128];
    int t = threadIdx.x;
    int g0 = blockIdx.x * 4;
#pragma unroll
    for (int i = 0; i < 32; ++i) W1s[t + i * 256] = W1[t + i * 256];
    for (int i = t; i < 4 * 128; i += 256) hgs[i] = hg[(size_t)g0 * H + i];
    __syncthreads();
    int g = t >> 6, c = t & 63;
    float acc = b1[c];
    const float* row = hgs + g * 128;
    for (int j = 0; j < 128; ++j) acc += row[j] * W1s[j * 64 + c];
    x1[(g0 + g) * 64 + c] = acc;
}

template <int C>
__global__ __launch_bounds__(1024) void k_bnstats(const float* __restrict__ x,
                                                  float* __restrict__ stats) {
    __shared__ float red[1024];
    __shared__ float mus[C];
    int t = threadIdx.x;
    int c = t & (C - 1), rc = t / C;
    const int R = 1024 / C;
    float s = 0.f;
    for (int g = rc; g < NG; g += R) s += x[g * C + c];
    red[t] = s;
    __syncthreads();
    if (t < C) {
        float S = 0.f;
        for (int i = 0; i < R; ++i) S += red[i * C + t];
        float mu = S / NG;
        mus[t] = mu;
        stats[t] = mu;
    }
    __syncthreads();
    float mu = mus[c];
    float s2 = 0.f;
    for (int g = rc; g < NG; g += R) {
        float d = x[g * C + c] - mu;
        s2 += d * d;
    }
    red[t] = s2;
    __syncthreads();
    if (t < C) {
        float Q = 0.f;
        for (int i = 0; i < R; ++i) Q += red[i * C + t];
        stats[C + t] = rsqrtf(Q / NG + 1e-5f);
    }
}

__global__ __launch_bounds__(256) void k_mlp2f(const float* __restrict__ x1,
                                               const float* __restrict__ st,
                                               const float* __restrict__ g1,
                                               const float* __restrict__ be1,
                                               const float* __restrict__ W2,
                                               const float* __restrict__ b2,
                                               float* __restrict__ x2) {
    __shared__ float W2s[64 * 32];
    __shared__ float x1s[8 * 64];
    int t = threadIdx.x;
    int g0 = blockIdx.x * 8;
#pragma unroll
    for (int i = 0; i < 8; ++i) W2s[t + i * 256] = W2[t + i * 256];
#pragma unroll
    for (int i = 0; i < 2; ++i) {
        int idx = t + i * 256;
        int c = idx & 63;
        float v = x1[(size_t)g0 * 64 + idx];
        v = (v - st[c]) * st[64 + c] * g1[c] + be1[c];
        x1s[idx] = lrelu(v);
    }
    __syncthreads();
    int g = t >> 5, c = t & 31;
    float acc = b2[c];
    const float* row = x1s + g * 64;
    for (int j = 0; j < 64; ++j) acc += row[j] * W2s[j * 32 + c];
    x2[(g0 + g) * 32 + c] = acc;
}

__global__ __launch_bounds__(256) void k_mlp3f(const float* __restrict__ x2,
                                               const float* __restrict__ st,
                                               const float* __restrict__ g2,
                                               const float* __restrict__ be2,
                                               const float* __restrict__ W3,
                                               const float* __restrict__ b3,
                                               float* __restrict__ out) {
    int g = blockIdx.x * blockDim.x + threadIdx.x;
    if (g >= NG) return;
    float acc = b3[0];
    for (int j = 0; j < 32; ++j) {
        float v = (x2[g * 32 + j] - st[j]) * st[32 + j] * g2[j] + be2[j];
        acc += lrelu(v) * W3[j];
    }
    out[g] = acc;
}

extern "C" void kernel_launch(void* const* d_in, const int* in_sizes, int n_in,
                              void* d_out, int out_size, void* d_ws, size_t ws_size,
                              hipStream_t stream) {
    const int* nfeats = (const int*)d_in[0];
    const int* src = (const int*)d_in[2];
    const int* dst = (const int*)d_in[3];
    const int* gid = (const int*)d_in[4];
    const float* emb = (const float*)d_in[5];
    const float* Wq = (const float*)d_in[6];
    const float* bq = (const float*)d_in[7];
    const float* Wk = (const float*)d_in[8];
    const float* bk = (const float*)d_in[9];
    const float* Wr = (const float*)d_in[10];
    const float* br = (const float*)d_in[11];
    const float* W1 = (const float*)d_in[12];
    const float* b1 = (const float*)d_in[13];
    const float* g1 = (const float*)d_in[14];
    const float* be1 = (const float*)d_in[15];
    const float* W2 = (const float*)d_in[16];
    const float* b2 = (const float*)d_in[17];
    const float* g2 = (const float*)d_in[18];
    const float* be2 = (const float*)d_in[19];
    const float* W3 = (const float*)d_in[20];
    const float* b3 = (const float*)d_in[21];
    float* out = (float*)d_out;

    size_t nh = (size_t)NP * H;
    unsigned short* P0 = (unsigned short*)d_ws;
    unsigned short* P1 = P0 + nh;
    unsigned short* P2 = P1 + nh;
    unsigned short* WT = P2 + nh;
    float* hg = (float*)(WT + 12 * H * H);
    float* x1 = hg + (size_t)NG * H;
    float* x2 = x1 + (size_t)NG * 64;
    float* st = x2 + (size_t)NG * 32;
    int* cursor = (int*)(st + 2 * 64);
    int* rowp = cursor + NN;
    int* bsum = rowp + NN + 1;
    int* csr_src = bsum + 128;
    int* gstart = csr_src + NE;

    // ---- CSR build + graph boundaries ----
    hipMemsetAsync(cursor, 0, NN * sizeof(int), stream);
    k_hist<<<(NE + 255) / 256, 256, 0, stream>>>(dst, cursor);
    k_scan1<<<SCAN_BLOCKS, 1024, 0, stream>>>(cursor, rowp, bsum);
    k_scan2<<<1, 128, 0, stream>>>(bsum);
    k_scan3<<<(NN + 255) / 256, 256, 0, stream>>>(bsum, rowp, cursor);
    k_scatter<<<(NE + 255) / 256, 256, 0, stream>>>(src, dst, cursor, csr_src);
    k_gbound<<<(NG + 256) / 256, 256, 0, stream>>>(gid, gstart);

    // ---- weight prep + atom encoder ----
    k_wt<<<12, 256, 0, stream>>>(Wq, Wk, Wr, WT);
    k_atom<<<NN / 4, 256, 0, stream>>>(nfeats, emb, P0);

    const int NB = NP / 128;  // 782
    // layer 0 q/k
    k_qk_mfma<<<NB, 256, 0, stream>>>(P0, WT + 0 * H * H, bq, WT + 1 * H * H, bk, P1, P2);
    for (int l = 0; l < NLAYER; ++l) {
        // agg: reads P1(q),P2(k) -> writes P0
        k_agg<<<(NN + 3) / 4, 256, 0, stream>>>(P1, P2, rowp, csr_src, P0);
        if (l < NLAYER - 1) {
            // fused: h_new stays in LDS; produces next layer's q,k
            k_rqk_mfma<<<NB, 256, 0, stream>>>(P0, WT + (size_t)(l * 3 + 2) * H * H, br + l * H,
                                               WT + (size_t)((l + 1) * 3 + 0) * H * H, bq + (l + 1) * H,
                                               WT + (size_t)((l + 1) * 3 + 1) * H * H, bk + (l + 1) * H,
                                               P1, P2);
        } else {
            // final layer: materialize h for pooling
            k_r_mfma<<<NB, 256, 0, stream>>>(P0, WT + (size_t)(l * 3 + 2) * H * H, br + l * H, P1);
        }
    }

    k_pool_seg<<<(NG + 3) / 4, 256, 0, stream>>>(P1, gstart, hg);

    // ---- MLP head ----
    k_mlp1<<<NG / 4, 256, 0, stream>>>(hg, W1, b1, x1);
    k_bnstats<64><<<1, 1024, 0, stream>>>(x1, st);
    k_mlp2f<<<NG / 8, 256, 0, stream>>>(x1, st, g1, be1, W2, b2, x2);
    k_bnstats<32><<<1, 1024, 0, stream>>>(x2, st);
    k_mlp3f<<<(NG + 255) / 256, 256, 0, stream>>>(x2, st, g2, be2, W3, b3, out);
}

// Round 8
// 734.671 us; speedup vs baseline: 2.5891x; 1.0247x over previous
//
#include <hip/hip_runtime.h>

#define NN 100000
#define NP 100096   // padded rows (782 blocks * 128)
#define NE 1000000
#define NG 1000
#define H 128
#define NLAYER 4
#define NEG 0.2f
#define SCAN_BLOCKS 98

using short8 = __attribute__((ext_vector_type(8))) short;
using fx4 = __attribute__((ext_vector_type(4))) float;

__device__ __forceinline__ float lrelu(float x) { return x >= 0.f ? x : NEG * x; }

__device__ __forceinline__ unsigned short f2bf(float f) {
    union { float f; unsigned int u; } v;
    v.f = f;
    return (unsigned short)((v.u + 0x7fffu + ((v.u >> 16) & 1u)) >> 16);
}
__device__ __forceinline__ float bf2f(unsigned short h) {
    union { unsigned int u; float f; } v;
    v.u = ((unsigned int)h) << 16;
    return v.f;
}
__device__ __forceinline__ float bflo(unsigned int u) {
    union { unsigned int x; float f; } v;
    v.x = u << 16;
    return v.f;
}
__device__ __forceinline__ float bfhi(unsigned int u) {
    union { unsigned int x; float f; } v;
    v.x = u & 0xffff0000u;
    return v.f;
}

// ---------------- Atom encoder ----------------
__global__ __launch_bounds__(256) void k_atom(const int* __restrict__ nfeats,
                                              const float* __restrict__ emb,
                                              unsigned short* __restrict__ h) {
    int node = blockIdx.x * 4 + (threadIdx.x >> 6);
    if (node >= NN) return;
    int lane = threadIdx.x & 63;
    int c = lane * 2;
    float ax = 0.f, ay = 0.f;
#pragma unroll
    for (int f = 0; f < 9; ++f) {
        int idx = nfeats[node * 9 + f];
        float2 e = *(const float2*)(emb + (size_t)((f << 6) + idx) * H + c);
        ax += e.x;
        ay += e.y;
    }
    unsigned int packed = (unsigned int)f2bf(ax) | ((unsigned int)f2bf(ay) << 16);
    *(unsigned int*)(h + (size_t)node * H + c) = packed;
}

// ---------------- Weight prep ----------------
__global__ __launch_bounds__(256) void k_wt(const float* __restrict__ Wq,
                                            const float* __restrict__ Wk,
                                            const float* __restrict__ Wr,
                                            unsigned short* __restrict__ WT) {
    int mat = blockIdx.x;
    int l = mat / 3;
    int kind = mat - l * 3;
    const float* src = (kind == 0 ? Wq : kind == 1 ? Wk : Wr) + (size_t)l * H * H;
    unsigned short* dst = WT + (size_t)mat * H * H;
    for (int idx = threadIdx.x; idx < H * H; idx += 256) {
        int kk = idx >> 7, n = idx & 127;
        dst[n * H + kk] = f2bf(src[idx]);
    }
}

// ---------------- CSR build ----------------
// 4 edges per thread via int4
__global__ __launch_bounds__(256) void k_hist(const int* __restrict__ dst, int* __restrict__ deg) {
    int i = blockIdx.x * blockDim.x + threadIdx.x;
    if (i * 4 >= NE) return;
    int4 d = *(const int4*)(dst + i * 4);
    atomicAdd(&deg[d.x], 1);
    atomicAdd(&deg[d.y], 1);
    atomicAdd(&deg[d.z], 1);
    atomicAdd(&deg[d.w], 1);
}

__global__ __launch_bounds__(1024) void k_scan1(const int* __restrict__ deg,
                                                int* __restrict__ rowp,
                                                int* __restrict__ bsum) {
    __shared__ int tmp[1024];
    int t = threadIdx.x;
    int i = blockIdx.x * 1024 + t;
    int v = (i < NN) ? deg[i] : 0;
    tmp[t] = v;
    __syncthreads();
    for (int off = 1; off < 1024; off <<= 1) {
        int u = (t >= off) ? tmp[t - off] : 0;
        __syncthreads();
        tmp[t] += u;
        __syncthreads();
    }
    if (i < NN) rowp[i] = tmp[t] - v;
    if (t == 1023) bsum[blockIdx.x] = tmp[1023];
}

__global__ __launch_bounds__(128) void k_scan2(int* __restrict__ bsum) {
    __shared__ int tmp[128];
    int t = threadIdx.x;
    int v = (t < SCAN_BLOCKS) ? bsum[t] : 0;
    tmp[t] = v;
    __syncthreads();
    for (int off = 1; off < 128; off <<= 1) {
        int u = (t >= off) ? tmp[t - off] : 0;
        __syncthreads();
        tmp[t] += u;
        __syncthreads();
    }
    if (t < SCAN_BLOCKS) bsum[t] = tmp[t] - v;
}

// scan3 (391 blocks) + gbound (4 blocks) merged
#define SCAN3_BLOCKS ((NN + 255) / 256)
__global__ __launch_bounds__(256) void k_scan3g(const int* __restrict__ bsum,
                                                int* __restrict__ rowp,
                                                int* __restrict__ cursor,
                                                const int* __restrict__ gid,
                                                int* __restrict__ gstart) {
    int bid = blockIdx.x;
    int t = threadIdx.x;
    if (bid < SCAN3_BLOCKS) {
        int i = bid * 256 + t;
        if (i < NN) {
            int v = rowp[i] + bsum[i >> 10];
            rowp[i] = v;
            cursor[i] = v;
        }
        if (i == 0) rowp[NN] = NE;
    } else {
        int g = (bid - SCAN3_BLOCKS) * 256 + t;
        if (g > NG) return;
        if (g == NG) { gstart[NG] = NN; return; }
        int lo = 0, hi = NN;
        while (lo < hi) {
            int mid = (lo + hi) >> 1;
            if (gid[mid] < g) lo = mid + 1; else hi = mid;
        }
        gstart[g] = lo;
    }
}

// 4 edges per thread via int4
__global__ __launch_bounds__(256) void k_scatter(const int* __restrict__ src,
                                                 const int* __restrict__ dst,
                                                 int* __restrict__ cursor,
                                                 int* __restrict__ csr_src) {
    int i = blockIdx.x * blockDim.x + threadIdx.x;
    if (i * 4 >= NE) return;
    int4 s = *(const int4*)(src + i * 4);
    int4 d = *(const int4*)(dst + i * 4);
    csr_src[atomicAdd(&cursor[d.x], 1)] = s.x;
    csr_src[atomicAdd(&cursor[d.y], 1)] = s.y;
    csr_src[atomicAdd(&cursor[d.z], 1)] = s.z;
    csr_src[atomicAdd(&cursor[d.w], 1)] = s.w;
}

// ---------------- fused q/k GEMM via MFMA (layer 0 entry) ----------------
__global__ __launch_bounds__(256) void k_qk_mfma(const unsigned short* __restrict__ h,
                                                 const unsigned short* __restrict__ WTq,
                                                 const float* __restrict__ bq,
                                                 const unsigned short* __restrict__ WTk,
                                                 const float* __restrict__ bk,
                                                 unsigned short* __restrict__ q,
                                                 unsigned short* __restrict__ k) {
    int lane = threadIdx.x & 63;
    int wave = threadIdx.x >> 6;
    int row0 = blockIdx.x * 128 + wave * 32;
    int lrow = lane & 15;
    int lk = (lane >> 4) << 3;

    short8 a[2][4];
#pragma unroll
    for (int rt = 0; rt < 2; ++rt)
#pragma unroll
        for (int ks = 0; ks < 4; ++ks)
            a[rt][ks] = *(const short8*)(h + (size_t)(row0 + rt * 16 + lrow) * H + ks * 32 + lk);

    fx4 aq[2][8], ak[2][8];
#pragma unroll
    for (int ct = 0; ct < 8; ++ct) {
        float vq = bq[ct * 16 + lrow];
        float vk = bk[ct * 16 + lrow];
#pragma unroll
        for (int rt = 0; rt < 2; ++rt) {
            aq[rt][ct] = fx4{vq, vq, vq, vq};
            ak[rt][ct] = fx4{vk, vk, vk, vk};
        }
    }

#pragma unroll
    for (int ks = 0; ks < 4; ++ks)
#pragma unroll
        for (int ct = 0; ct < 8; ++ct) {
            short8 wq = *(const short8*)(WTq + (ct * 16 + lrow) * H + ks * 32 + lk);
            short8 wk = *(const short8*)(WTk + (ct * 16 + lrow) * H + ks * 32 + lk);
#pragma unroll
            for (int rt = 0; rt < 2; ++rt) {
                aq[rt][ct] = __builtin_amdgcn_mfma_f32_16x16x32_bf16(a[rt][ks], wq, aq[rt][ct], 0, 0, 0);
                ak[rt][ct] = __builtin_amdgcn_mfma_f32_16x16x32_bf16(a[rt][ks], wk, ak[rt][ct], 0, 0, 0);
            }
        }

#pragma unroll
    for (int rt = 0; rt < 2; ++rt)
#pragma unroll
        for (int ct = 0; ct < 8; ++ct)
#pragma unroll
            for (int rg = 0; rg < 4; ++rg) {
                int r = row0 + rt * 16 + ((lane >> 4) << 2) + rg;
                if (r < NN) {
                    q[(size_t)r * H + ct * 16 + lrow] = f2bf(aq[rt][ct][rg]);
                    k[(size_t)r * H + ct * 16 + lrow] = f2bf(ak[rt][ct][rg]);
                }
            }
}

// ---------------- h_new = lrelu(agg@Wr + br) via MFMA (final layer) ----------------
__global__ __launch_bounds__(256) void k_r_mfma(const unsigned short* __restrict__ agg,
                                                const unsigned short* __restrict__ WTr,
                                                const float* __restrict__ br,
                                                unsigned short* __restrict__ hout) {
    int lane = threadIdx.x & 63;
    int wave = threadIdx.x >> 6;
    int row0 = blockIdx.x * 128 + wave * 32;
    int lrow = lane & 15;
    int lk = (lane >> 4) << 3;

    short8 a[2][4];
#pragma unroll
    for (int rt = 0; rt < 2; ++rt)
#pragma unroll
        for (int ks = 0; ks < 4; ++ks)
            a[rt][ks] = *(const short8*)(agg + (size_t)(row0 + rt * 16 + lrow) * H + ks * 32 + lk);

    fx4 acc[2][8];
#pragma unroll
    for (int ct = 0; ct < 8; ++ct) {
        float v = br[ct * 16 + lrow];
#pragma unroll
        for (int rt = 0; rt < 2; ++rt) acc[rt][ct] = fx4{v, v, v, v};
    }

#pragma unroll
    for (int ks = 0; ks < 4; ++ks)
#pragma unroll
        for (int ct = 0; ct < 8; ++ct) {
            short8 w = *(const short8*)(WTr + (ct * 16 + lrow) * H + ks * 32 + lk);
#pragma unroll
            for (int rt = 0; rt < 2; ++rt)
                acc[rt][ct] = __builtin_amdgcn_mfma_f32_16x16x32_bf16(a[rt][ks], w, acc[rt][ct], 0, 0, 0);
        }

#pragma unroll
    for (int rt = 0; rt < 2; ++rt)
#pragma unroll
        for (int ct = 0; ct < 8; ++ct)
#pragma unroll
            for (int rg = 0; rg < 4; ++rg) {
                int r = row0 + rt * 16 + ((lane >> 4) << 2) + rg;
                if (r < NN)
                    hout[(size_t)r * H + ct * 16 + lrow] = f2bf(lrelu(acc[rt][ct][rg]));
            }
}

// ---------------- FUSED: h_new = lrelu(agg@Wr+br); q = h_new@Wq+bq; k = h_new@Wk+bk ----------------
__global__ __launch_bounds__(256) void k_rqk_mfma(const unsigned short* __restrict__ agg,
                                                  const unsigned short* __restrict__ WTr,
                                                  const float* __restrict__ br,
                                                  const unsigned short* __restrict__ WTq,
                                                  const float* __restrict__ bq,
                                                  const unsigned short* __restrict__ WTk,
                                                  const float* __restrict__ bk,
                                                  unsigned short* __restrict__ q,
                                                  unsigned short* __restrict__ k) {
    __shared__ unsigned short hls[4][32][136];  // 272B row stride: 16B-aligned, ~2-way banks
    int lane = threadIdx.x & 63;
    int wave = threadIdx.x >> 6;
    int row0 = blockIdx.x * 128 + wave * 32;
    int lrow = lane & 15;
    int lk = (lane >> 4) << 3;

    // ---- stage 1: h_new = lrelu(agg @ Wr + br) ----
    short8 a[2][4];
#pragma unroll
    for (int rt = 0; rt < 2; ++rt)
#pragma unroll
        for (int ks = 0; ks < 4; ++ks)
            a[rt][ks] = *(const short8*)(agg + (size_t)(row0 + rt * 16 + lrow) * H + ks * 32 + lk);

    fx4 acc[2][8];
#pragma unroll
    for (int ct = 0; ct < 8; ++ct) {
        float v = br[ct * 16 + lrow];
#pragma unroll
        for (int rt = 0; rt < 2; ++rt) acc[rt][ct] = fx4{v, v, v, v};
    }

#pragma unroll
    for (int ks = 0; ks < 4; ++ks)
#pragma unroll
        for (int ct = 0; ct < 8; ++ct) {
            short8 w = *(const short8*)(WTr + (ct * 16 + lrow) * H + ks * 32 + lk);
#pragma unroll
            for (int rt = 0; rt < 2; ++rt)
                acc[rt][ct] = __builtin_amdgcn_mfma_f32_16x16x32_bf16(a[rt][ks], w, acc[rt][ct], 0, 0, 0);
        }

    // C-layout -> LDS (wave-private slice)
#pragma unroll
    for (int rt = 0; rt < 2; ++rt)
#pragma unroll
        for (int ct = 0; ct < 8; ++ct)
#pragma unroll
            for (int rg = 0; rg < 4; ++rg) {
                int lr = rt * 16 + ((lane >> 4) << 2) + rg;
                hls[wave][lr][ct * 16 + lrow] = f2bf(lrelu(acc[rt][ct][rg]));
            }

    // ---- stage 2: A-fragments of h_new from LDS; q/k GEMM ----
    short8 a2[2][4];
#pragma unroll
    for (int rt = 0; rt < 2; ++rt)
#pragma unroll
        for (int ks = 0; ks < 4; ++ks)
            a2[rt][ks] = *(const short8*)&hls[wave][rt * 16 + lrow][ks * 32 + lk];

    fx4 aq[2][8], ak[2][8];
#pragma unroll
    for (int ct = 0; ct < 8; ++ct) {
        float vq = bq[ct * 16 + lrow];
        float vk = bk[ct * 16 + lrow];
#pragma unroll
        for (int rt = 0; rt < 2; ++rt) {
            aq[rt][ct] = fx4{vq, vq, vq, vq};
            ak[rt][ct] = fx4{vk, vk, vk, vk};
        }
    }

#pragma unroll
    for (int ks = 0; ks < 4; ++ks)
#pragma unroll
        for (int ct = 0; ct < 8; ++ct) {
            short8 wq = *(const short8*)(WTq + (ct * 16 + lrow) * H + ks * 32 + lk);
            short8 wk = *(const short8*)(WTk + (ct * 16 + lrow) * H + ks * 32 + lk);
#pragma unroll
            for (int rt = 0; rt < 2; ++rt) {
                aq[rt][ct] = __builtin_amdgcn_mfma_f32_16x16x32_bf16(a2[rt][ks], wq, aq[rt][ct], 0, 0, 0);
                ak[rt][ct] = __builtin_amdgcn_mfma_f32_16x16x32_bf16(a2[rt][ks], wk, ak[rt][ct], 0, 0, 0);
            }
        }

#pragma unroll
    for (int rt = 0; rt < 2; ++rt)
#pragma unroll
        for (int ct = 0; ct < 8; ++ct)
#pragma unroll
            for (int rg = 0; rg < 4; ++rg) {
                int r = row0 + rt * 16 + ((lane >> 4) << 2) + rg;
                if (r < NN) {
                    q[(size_t)r * H + ct * 16 + lrow] = f2bf(aq[rt][ct][rg]);
                    k[(size_t)r * H + ct * 16 + lrow] = f2bf(ak[rt][ct][rg]);
                }
            }
}

// ---------------- aggregation: 8 gathers in flight (2x4 edges), 16 lanes x 16B per edge ----------------
// All __shfl wave-uniform; shfl indices provably <= 63; loads unconditional on valid dummy row.
__global__ __launch_bounds__(256) void k_agg(const unsigned short* __restrict__ q,
                                             const unsigned short* __restrict__ kk,
                                             const int* __restrict__ rowp,
                                             const int* __restrict__ csr_src,
                                             unsigned short* __restrict__ agg) {
    int node = blockIdx.x * 4 + (threadIdx.x >> 6);
    if (node >= NN) return;
    int lane = threadIdx.x & 63;
    int qt = lane >> 4;   // which edge of the 4-pack
    int ql = lane & 15;   // 16 lanes cover one 256B row, 8 channels each
    int start = rowp[node];
    int end = rowp[node + 1];

    uint4 qp = *(const uint4*)(q + (size_t)node * H + ql * 8);
    float qv0 = bflo(qp.x), qv1 = bfhi(qp.x), qv2 = bflo(qp.y), qv3 = bfhi(qp.y);
    float qv4 = bflo(qp.z), qv5 = bfhi(qp.z), qv6 = bflo(qp.w), qv7 = bfhi(qp.w);
    float a0 = 0.f, a1 = 0.f, a2 = 0.f, a3 = 0.f, a4 = 0.f, a5 = 0.f, a6 = 0.f, a7 = 0.f;

    for (int base = start; base < end; base += 64) {
        int cnt = end - base;
        if (cnt > 64) cnt = 64;
        int sid = (lane < cnt) ? csr_src[base + lane] : 0;  // lanes >= cnt: valid dummy row 0
        int cnt8 = (cnt + 7) & ~7;
        for (int j = 0; j < cnt8; j += 8) {
            int jj0 = j + qt;           // <= 63
            int jj1 = j + 4 + qt;       // <= cnt8-8+4+3 <= 63
            int s0 = __shfl(sid, jj0);
            int s1 = __shfl(sid, jj1);
            uint4 kp0 = *(const uint4*)(kk + (size_t)s0 * H + ql * 8);
            uint4 kp1 = *(const uint4*)(kk + (size_t)s1 * H + ql * 8);
            if (jj0 < cnt) {
                a0 += lrelu(qv0 + bflo(kp0.x));
                a1 += lrelu(qv1 + bfhi(kp0.x));
                a2 += lrelu(qv2 + bflo(kp0.y));
                a3 += lrelu(qv3 + bfhi(kp0.y));
                a4 += lrelu(qv4 + bflo(kp0.z));
                a5 += lrelu(qv5 + bfhi(kp0.z));
                a6 += lrelu(qv6 + bflo(kp0.w));
                a7 += lrelu(qv7 + bfhi(kp0.w));
            }
            if (jj1 < cnt) {
                a0 += lrelu(qv0 + bflo(kp1.x));
                a1 += lrelu(qv1 + bfhi(kp1.x));
                a2 += lrelu(qv2 + bflo(kp1.y));
                a3 += lrelu(qv3 + bfhi(kp1.y));
                a4 += lrelu(qv4 + bflo(kp1.z));
                a5 += lrelu(qv5 + bfhi(kp1.z));
                a6 += lrelu(qv6 + bflo(kp1.w));
                a7 += lrelu(qv7 + bfhi(kp1.w));
            }
        }
    }
    // sum the 4 edge-groups (qt 0..3) -> every lane holds full sums
    a0 += __shfl_xor(a0, 16); a0 += __shfl_xor(a0, 32);
    a1 += __shfl_xor(a1, 16); a1 += __shfl_xor(a1, 32);
    a2 += __shfl_xor(a2, 16); a2 += __shfl_xor(a2, 32);
    a3 += __shfl_xor(a3, 16); a3 += __shfl_xor(a3, 32);
    a4 += __shfl_xor(a4, 16); a4 += __shfl_xor(a4, 32);
    a5 += __shfl_xor(a5, 16); a5 += __shfl_xor(a5, 32);
    a6 += __shfl_xor(a6, 16); a6 += __shfl_xor(a6, 32);
    a7 += __shfl_xor(a7, 16); a7 += __shfl_xor(a7, 32);
    if (qt == 0) {
        uint4 o;
        o.x = (unsigned int)f2bf(a0) | ((unsigned int)f2bf(a1) << 16);
        o.y = (unsigned int)f2bf(a2) | ((unsigned int)f2bf(a3) << 16);
        o.z = (unsigned int)f2bf(a4) | ((unsigned int)f2bf(a5) << 16);
        o.w = (unsigned int)f2bf(a6) | ((unsigned int)f2bf(a7) << 16);
        *(uint4*)(agg + (size_t)node * H + ql * 8) = o;
    }
}

// ---------------- segmented graph pooling ----------------
__global__ __launch_bounds__(256) void k_pool_seg(const unsigned short* __restrict__ h,
                                                  const int* __restrict__ gstart,
                                                  float* __restrict__ hg) {
    int g = blockIdx.x * 4 + (threadIdx.x >> 6);
    if (g >= NG) return;
    int lane = threadIdx.x & 63;
    int s = gstart[g], e = gstart[g + 1];
    float ax = 0.f, ay = 0.f;
    for (int n = s; n < e; ++n) {
        unsigned int hp = *(const unsigned int*)(h + (size_t)n * H + lane * 2);
        ax += bflo(hp);
        ay += bfhi(hp);
    }
    float2 o;
    o.x = ax;
    o.y = ay;
    *(float2*)(hg + (size_t)g * H + lane * 2) = o;
}

// ---------------- MLP head ----------------
__global__ __launch_bounds__(256) void k_mlp1(const float* __restrict__ hg,
                                              const float* __restrict__ W1,
                                              const float* __restrict__ b1,
                                              float* __restrict__ x1) {
    __shared__ float W1s[128 * 64];
    __shared__ float hgs[4 * 128];
    int t = threadIdx.x;
    int g0 = blockIdx.x * 4;
#pragma unroll
    for (int i = 0; i < 32; ++i) W1s[t + i * 256] = W1[t + i * 256];
    for (int i = t; i < 4 * 128; i += 256) hgs[i] = hg[(size_t)g0 * H + i];
    __syncthreads();
    int g = t >> 6, c = t & 63;
    float acc = b1[c];
    const float* row = hgs + g * 128;
    for (int j = 0; j < 128; ++j) acc += row[j] * W1s[j * 64 + c];
    x1[(g0 + g) * 64 + c] = acc;
}

template <int C>
__global__ __launch_bounds__(1024) void k_bnstats(const float* __restrict__ x,
                                                  float* __restrict__ stats) {
    __shared__ float red[1024];
    __shared__ float mus[C];
    int t = threadIdx.x;
    int c = t & (C - 1), rc = t / C;
    const int R = 1024 / C;
    float s = 0.f;
    for (int g = rc; g < NG; g += R) s += x[g * C + c];
    red[t] = s;
    __syncthreads();
    if (t < C) {
        float S = 0.f;
        for (int i = 0; i < R; ++i) S += red[i * C + t];
        float mu = S / NG;
        mus[t] = mu;
        stats[t] = mu;
    }
    __syncthreads();
    float mu = mus[c];
    float s2 = 0.f;
    for (int g = rc; g < NG; g += R) {
        float d = x[g * C + c] - mu;
        s2 += d * d;
    }
    red[t] = s2;
    __syncthreads();
    if (t < C) {
        float Q = 0.f;
        for (int i = 0; i < R; ++i) Q += red[i * C + t];
        stats[C + t] = rsqrtf(Q / NG + 1e-5f);
    }
}

__global__ __launch_bounds__(256) void k_mlp2f(const float* __restrict__ x1,
                                               const float* __restrict__ st,
                                               const float* __restrict__ g1,
                                               const float* __restrict__ be1,
                                               const float* __restrict__ W2,
                                               const float* __restrict__ b2,
                                               float* __restrict__ x2) {
    __shared__ float W2s[64 * 32];
    __shared__ float x1s[8 * 64];
    int t = threadIdx.x;
    int g0 = blockIdx.x * 8;
#pragma unroll
    for (int i = 0; i < 8; ++i) W2s[t + i * 256] = W2[t + i * 256];
#pragma unroll
    for (int i = 0; i < 2; ++i) {
        int idx = t + i * 256;
        int c = idx & 63;
        float v = x1[(size_t)g0 * 64 + idx];
        v = (v - st[c]) * st[64 + c] * g1[c] + be1[c];
        x1s[idx] = lrelu(v);
    }
    __syncthreads();
    int g = t >> 5, c = t & 31;
    float acc = b2[c];
    const float* row = x1s + g * 64;
    for (int j = 0; j < 64; ++j) acc += row[j] * W2s[j * 32 + c];
    x2[(g0 + g) * 32 + c] = acc;
}

__global__ __launch_bounds__(256) void k_mlp3f(const float* __restrict__ x2,
                                               const float* __restrict__ st,
                                               const float* __restrict__ g2,
                                               const float* __restrict__ be2,
                                               const float* __restrict__ W3,
                                               const float* __restrict__ b3,
                                               float* __restrict__ out) {
    int g = blockIdx.x * blockDim.x + threadIdx.x;
    if (g >= NG) return;
    float acc = b3[0];
    for (int j = 0; j < 32; ++j) {
        float v = (x2[g * 32 + j] - st[j]) * st[32 + j] * g2[j] + be2[j];
        acc += lrelu(v) * W3[j];
    }
    out[g] = acc;
}

extern "C" void kernel_launch(void* const* d_in, const int* in_sizes, int n_in,
                              void* d_out, int out_size, void* d_ws, size_t ws_size,
                              hipStream_t stream) {
    const int* nfeats = (const int*)d_in[0];
    const int* src = (const int*)d_in[2];
    const int* dst = (const int*)d_in[3];
    const int* gid = (const int*)d_in[4];
    const float* emb = (const float*)d_in[5];
    const float* Wq = (const float*)d_in[6];
    const float* bq = (const float*)d_in[7];
    const float* Wk = (const float*)d_in[8];
    const float* bk = (const float*)d_in[9];
    const float* Wr = (const float*)d_in[10];
    const float* br = (const float*)d_in[11];
    const float* W1 = (const float*)d_in[12];
    const float* b1 = (const float*)d_in[13];
    const float* g1 = (const float*)d_in[14];
    const float* be1 = (const float*)d_in[15];
    const float* W2 = (const float*)d_in[16];
    const float* b2 = (const float*)d_in[17];
    const float* g2 = (const float*)d_in[18];
    const float* be2 = (const float*)d_in[19];
    const float* W3 = (const float*)d_in[20];
    const float* b3 = (const float*)d_in[21];
    float* out = (float*)d_out;

    size_t nh = (size_t)NP * H;
    unsigned short* P0 = (unsigned short*)d_ws;
    unsigned short* P1 = P0 + nh;
    unsigned short* P2 = P1 + nh;
    unsigned short* WT = P2 + nh;
    float* hg = (float*)(WT + 12 * H * H);
    float* x1 = hg + (size_t)NG * H;
    float* x2 = x1 + (size_t)NG * 64;
    float* st = x2 + (size_t)NG * 32;
    int* cursor = (int*)(st + 2 * 64);
    int* rowp = cursor + NN;
    int* bsum = rowp + NN + 1;
    int* csr_src = bsum + 128;
    int* gstart = csr_src + NE;

    // ---- CSR build + graph boundaries ----
    hipMemsetAsync(cursor, 0, NN * sizeof(int), stream);
    k_hist<<<(NE / 4 + 255) / 256, 256, 0, stream>>>(dst, cursor);
    k_scan1<<<SCAN_BLOCKS, 1024, 0, stream>>>(cursor, rowp, bsum);
    k_scan2<<<1, 128, 0, stream>>>(bsum);
    k_scan3g<<<SCAN3_BLOCKS + 4, 256, 0, stream>>>(bsum, rowp, cursor, gid, gstart);
    k_scatter<<<(NE / 4 + 255) / 256, 256, 0, stream>>>(src, dst, cursor, csr_src);

    // ---- weight prep + atom encoder ----
    k_wt<<<12, 256, 0, stream>>>(Wq, Wk, Wr, WT);
    k_atom<<<NN / 4, 256, 0, stream>>>(nfeats, emb, P0);

    const int NB = NP / 128;  // 782
    // layer 0 q/k
    k_qk_mfma<<<NB, 256, 0, stream>>>(P0, WT + 0 * H * H, bq, WT + 1 * H * H, bk, P1, P2);
    for (int l = 0; l < NLAYER; ++l) {
        // agg: reads P1(q),P2(k) -> writes P0
        k_agg<<<(NN + 3) / 4, 256, 0, stream>>>(P1, P2, rowp, csr_src, P0);
        if (l < NLAYER - 1) {
            // fused: h_new stays in LDS; produces next layer's q,k
            k_rqk_mfma<<<NB, 256, 0, stream>>>(P0, WT + (size_t)(l * 3 + 2) * H * H, br + l * H,
                                               WT + (size_t)((l + 1) * 3 + 0) * H * H, bq + (l + 1) * H,
                                               WT + (size_t)((l + 1) * 3 + 1) * H * H, bk + (l + 1) * H,
                                               P1, P2);
        } else {
            // final layer: materialize h for pooling
            k_r_mfma<<<NB, 256, 0, stream>>>(P0, WT + (size_t)(l * 3 + 2) * H * H, br + l * H, P1);
        }
    }

    k_pool_seg<<<(NG + 3) / 4, 256, 0, stream>>>(P1, gstart, hg);

    // ---- MLP head ----
    k_mlp1<<<NG / 4, 256, 0, stream>>>(hg, W1, b1, x1);
    k_bnstats<64><<<1, 1024, 0, stream>>>(x1, st);
    k_mlp2f<<<NG / 8, 256, 0, stream>>>(x1, st, g1, be1, W2, b2, x2);
    k_bnstats<32><<<1, 1024, 0, stream>>>(x2, st);
    k_mlp3f<<<(NG + 255) / 256, 256, 0, stream>>>(x2, st, g2, be2, W3, b3, out);
}

// Round 9
// 730.381 us; speedup vs baseline: 2.6043x; 1.0059x over previous
//
#include <hip/hip_runtime.h>

#define NN 100000
#define NP 100096   // padded rows (782 blocks * 128)
#define NE 1000000
#define NG 1000
#define H 128
#define NLAYER 4
#define NEG 0.2f
#define SCAN_BLOCKS 98

using short8 = __attribute__((ext_vector_type(8))) short;
using fx4 = __attribute__((ext_vector_type(4))) float;

__device__ __forceinline__ float lrelu(float x) { return x >= 0.f ? x : NEG * x; }

__device__ __forceinline__ unsigned short f2bf(float f) {
    union { float f; unsigned int u; } v;
    v.f = f;
    return (unsigned short)((v.u + 0x7fffu + ((v.u >> 16) & 1u)) >> 16);
}
__device__ __forceinline__ float bflo(unsigned int u) {
    union { unsigned int x; float f; } v;
    v.x = u << 16;
    return v.f;
}
__device__ __forceinline__ float bfhi(unsigned int u) {
    union { unsigned int x; float f; } v;
    v.x = u & 0xffff0000u;
    return v.f;
}

// ---------------- Weight prep ----------------
__global__ __launch_bounds__(256) void k_wt(const float* __restrict__ Wq,
                                            const float* __restrict__ Wk,
                                            const float* __restrict__ Wr,
                                            unsigned short* __restrict__ WT) {
    int mat = blockIdx.x;
    int l = mat / 3;
    int kind = mat - l * 3;
    const float* src = (kind == 0 ? Wq : kind == 1 ? Wk : Wr) + (size_t)l * H * H;
    unsigned short* dst = WT + (size_t)mat * H * H;
    for (int idx = threadIdx.x; idx < H * H; idx += 256) {
        int kk = idx >> 7, n = idx & 127;
        dst[n * H + kk] = f2bf(src[idx]);
    }
}

// ---------------- CSR build ----------------
__global__ __launch_bounds__(256) void k_hist(const int* __restrict__ dst, int* __restrict__ deg) {
    int i = blockIdx.x * blockDim.x + threadIdx.x;
    if (i * 4 >= NE) return;
    int4 d = *(const int4*)(dst + i * 4);
    atomicAdd(&deg[d.x], 1);
    atomicAdd(&deg[d.y], 1);
    atomicAdd(&deg[d.z], 1);
    atomicAdd(&deg[d.w], 1);
}

__global__ __launch_bounds__(1024) void k_scan1(const int* __restrict__ deg,
                                                int* __restrict__ rowp,
                                                int* __restrict__ bsum) {
    __shared__ int tmp[1024];
    int t = threadIdx.x;
    int i = blockIdx.x * 1024 + t;
    int v = (i < NN) ? deg[i] : 0;
    tmp[t] = v;
    __syncthreads();
    for (int off = 1; off < 1024; off <<= 1) {
        int u = (t >= off) ? tmp[t - off] : 0;
        __syncthreads();
        tmp[t] += u;
        __syncthreads();
    }
    if (i < NN) rowp[i] = tmp[t] - v;
    if (t == 1023) bsum[blockIdx.x] = tmp[1023];
}

__global__ __launch_bounds__(128) void k_scan2(int* __restrict__ bsum) {
    __shared__ int tmp[128];
    int t = threadIdx.x;
    int v = (t < SCAN_BLOCKS) ? bsum[t] : 0;
    tmp[t] = v;
    __syncthreads();
    for (int off = 1; off < 128; off <<= 1) {
        int u = (t >= off) ? tmp[t - off] : 0;
        __syncthreads();
        tmp[t] += u;
        __syncthreads();
    }
    if (t < SCAN_BLOCKS) bsum[t] = tmp[t] - v;
}

#define SCAN3_BLOCKS ((NN + 255) / 256)
__global__ __launch_bounds__(256) void k_scan3g(const int* __restrict__ bsum,
                                                int* __restrict__ rowp,
                                                int* __restrict__ cursor,
                                                const int* __restrict__ gid,
                                                int* __restrict__ gstart) {
    int bid = blockIdx.x;
    int t = threadIdx.x;
    if (bid < SCAN3_BLOCKS) {
        int i = bid * 256 + t;
        if (i < NN) {
            int v = rowp[i] + bsum[i >> 10];
            rowp[i] = v;
            cursor[i] = v;
        }
        if (i == 0) rowp[NN] = NE;
    } else {
        int g = (bid - SCAN3_BLOCKS) * 256 + t;
        if (g > NG) return;
        if (g == NG) { gstart[NG] = NN; return; }
        int lo = 0, hi = NN;
        while (lo < hi) {
            int mid = (lo + hi) >> 1;
            if (gid[mid] < g) lo = mid + 1; else hi = mid;
        }
        gstart[g] = lo;
    }
}

__global__ __launch_bounds__(256) void k_scatter(const int* __restrict__ src,
                                                 const int* __restrict__ dst,
                                                 int* __restrict__ cursor,
                                                 int* __restrict__ csr_src) {
    int i = blockIdx.x * blockDim.x + threadIdx.x;
    if (i * 4 >= NE) return;
    int4 s = *(const int4*)(src + i * 4);
    int4 d = *(const int4*)(dst + i * 4);
    csr_src[atomicAdd(&cursor[d.x], 1)] = s.x;
    csr_src[atomicAdd(&cursor[d.y], 1)] = s.y;
    csr_src[atomicAdd(&cursor[d.z], 1)] = s.z;
    csr_src[atomicAdd(&cursor[d.w], 1)] = s.w;
}

// ---------------- FUSED atom encoder + layer-0 q/k GEMM ----------------
// A-fragments computed directly from embedding table; h never materialized.
// Per-channel sum order over f identical to the old k_atom (bit-exact).
__global__ __launch_bounds__(256) void k_aqk_mfma(const int* __restrict__ nfeats,
                                                  const float* __restrict__ emb,
                                                  const unsigned short* __restrict__ WTq,
                                                  const float* __restrict__ bq,
                                                  const unsigned short* __restrict__ WTk,
                                                  const float* __restrict__ bk,
                                                  unsigned short* __restrict__ q,
                                                  unsigned short* __restrict__ k) {
    int lane = threadIdx.x & 63;
    int wave = threadIdx.x >> 6;
    int row0 = blockIdx.x * 128 + wave * 32;
    int lrow = lane & 15;
    int lk = (lane >> 4) << 3;

    short8 a[2][4];
#pragma unroll
    for (int rt = 0; rt < 2; ++rt) {
        int row = row0 + rt * 16 + lrow;
        int crow = row < NN ? row : NN - 1;  // clamp padded rows (stores guarded below)
        int fidx[9];
#pragma unroll
        for (int f = 0; f < 9; ++f) fidx[f] = nfeats[crow * 9 + f];
#pragma unroll
        for (int ks = 0; ks < 4; ++ks) {
            float s0 = 0.f, s1 = 0.f, s2 = 0.f, s3 = 0.f, s4 = 0.f, s5 = 0.f, s6 = 0.f, s7 = 0.f;
#pragma unroll
            for (int f = 0; f < 9; ++f) {
                const float* e = emb + (size_t)((f << 6) + fidx[f]) * H + ks * 32 + lk;
                float4 e0 = *(const float4*)e;
                float4 e1 = *(const float4*)(e + 4);
                s0 += e0.x; s1 += e0.y; s2 += e0.z; s3 += e0.w;
                s4 += e1.x; s5 += e1.y; s6 += e1.z; s7 += e1.w;
            }
            short8 v;
            v[0] = (short)f2bf(s0); v[1] = (short)f2bf(s1);
            v[2] = (short)f2bf(s2); v[3] = (short)f2bf(s3);
            v[4] = (short)f2bf(s4); v[5] = (short)f2bf(s5);
            v[6] = (short)f2bf(s6); v[7] = (short)f2bf(s7);
            a[rt][ks] = v;
        }
    }

    // 4 low-pressure passes: {q, k} x {ct 0-3, ct 4-7}
#pragma unroll
    for (int pass = 0; pass < 4; ++pass) {
        const unsigned short* W = (pass < 2) ? WTq : WTk;
        const float* b = (pass < 2) ? bq : bk;
        unsigned short* o = (pass < 2) ? q : k;
        int c0 = (pass & 1) * 4;
        fx4 acc[2][4];
#pragma unroll
        for (int ct = 0; ct < 4; ++ct) {
            float v = b[(c0 + ct) * 16 + lrow];
#pragma unroll
            for (int rt = 0; rt < 2; ++rt) acc[rt][ct] = fx4{v, v, v, v};
        }
#pragma unroll
        for (int ks = 0; ks < 4; ++ks)
#pragma unroll
            for (int ct = 0; ct < 4; ++ct) {
                short8 w = *(const short8*)(W + ((c0 + ct) * 16 + lrow) * H + ks * 32 + lk);
#pragma unroll
                for (int rt = 0; rt < 2; ++rt)
                    acc[rt][ct] = __builtin_amdgcn_mfma_f32_16x16x32_bf16(a[rt][ks], w, acc[rt][ct], 0, 0, 0);
            }
#pragma unroll
        for (int rt = 0; rt < 2; ++rt)
#pragma unroll
            for (int ct = 0; ct < 4; ++ct)
#pragma unroll
                for (int rg = 0; rg < 4; ++rg) {
                    int r = row0 + rt * 16 + ((lane >> 4) << 2) + rg;
                    if (r < NN)
                        o[(size_t)r * H + (c0 + ct) * 16 + lrow] = f2bf(acc[rt][ct][rg]);
                }
    }
}

// ---------------- h_new = lrelu(agg@Wr + br) via MFMA (final layer), ct-split ----------------
__global__ __launch_bounds__(256) void k_r_mfma(const unsigned short* __restrict__ agg,
                                                const unsigned short* __restrict__ WTr,
                                                const float* __restrict__ br,
                                                unsigned short* __restrict__ hout) {
    int lane = threadIdx.x & 63;
    int wave = threadIdx.x >> 6;
    int row0 = blockIdx.x * 128 + wave * 32;
    int lrow = lane & 15;
    int lk = (lane >> 4) << 3;

    short8 a[2][4];
#pragma unroll
    for (int rt = 0; rt < 2; ++rt)
#pragma unroll
        for (int ks = 0; ks < 4; ++ks)
            a[rt][ks] = *(const short8*)(agg + (size_t)(row0 + rt * 16 + lrow) * H + ks * 32 + lk);

#pragma unroll
    for (int chf = 0; chf < 2; ++chf) {
        int c0 = chf * 4;
        fx4 acc[2][4];
#pragma unroll
        for (int ct = 0; ct < 4; ++ct) {
            float v = br[(c0 + ct) * 16 + lrow];
#pragma unroll
            for (int rt = 0; rt < 2; ++rt) acc[rt][ct] = fx4{v, v, v, v};
        }
#pragma unroll
        for (int ks = 0; ks < 4; ++ks)
#pragma unroll
            for (int ct = 0; ct < 4; ++ct) {
                short8 w = *(const short8*)(WTr + ((c0 + ct) * 16 + lrow) * H + ks * 32 + lk);
#pragma unroll
                for (int rt = 0; rt < 2; ++rt)
                    acc[rt][ct] = __builtin_amdgcn_mfma_f32_16x16x32_bf16(a[rt][ks], w, acc[rt][ct], 0, 0, 0);
            }
#pragma unroll
        for (int rt = 0; rt < 2; ++rt)
#pragma unroll
            for (int ct = 0; ct < 4; ++ct)
#pragma unroll
                for (int rg = 0; rg < 4; ++rg) {
                    int r = row0 + rt * 16 + ((lane >> 4) << 2) + rg;
                    if (r < NN)
                        hout[(size_t)r * H + (c0 + ct) * 16 + lrow] = f2bf(lrelu(acc[rt][ct][rg]));
                }
    }
}

// ---------------- FUSED: h_new = lrelu(agg@Wr+br); q = h_new@Wq+bq; k = h_new@Wk+bk ----------------
__global__ __launch_bounds__(256) void k_rqk_mfma(const unsigned short* __restrict__ agg,
                                                  const unsigned short* __restrict__ WTr,
                                                  const float* __restrict__ br,
                                                  const unsigned short* __restrict__ WTq,
                                                  const float* __restrict__ bq,
                                                  const unsigned short* __restrict__ WTk,
                                                  const float* __restrict__ bk,
                                                  unsigned short* __restrict__ q,
                                                  unsigned short* __restrict__ k) {
    __shared__ unsigned short hls[4][32][136];  // 272B row stride: 16B-aligned
    int lane = threadIdx.x & 63;
    int wave = threadIdx.x >> 6;
    int row0 = blockIdx.x * 128 + wave * 32;
    int lrow = lane & 15;
    int lk = (lane >> 4) << 3;

    // ---- stage 1: h_new = lrelu(agg @ Wr + br), ct-split ----
    short8 a[2][4];
#pragma unroll
    for (int rt = 0; rt < 2; ++rt)
#pragma unroll
        for (int ks = 0; ks < 4; ++ks)
            a[rt][ks] = *(const short8*)(agg + (size_t)(row0 + rt * 16 + lrow) * H + ks * 32 + lk);

#pragma unroll
    for (int chf = 0; chf < 2; ++chf) {
        int c0 = chf * 4;
        fx4 acc[2][4];
#pragma unroll
        for (int ct = 0; ct < 4; ++ct) {
            float v = br[(c0 + ct) * 16 + lrow];
#pragma unroll
            for (int rt = 0; rt < 2; ++rt) acc[rt][ct] = fx4{v, v, v, v};
        }
#pragma unroll
        for (int ks = 0; ks < 4; ++ks)
#pragma unroll
            for (int ct = 0; ct < 4; ++ct) {
                short8 w = *(const short8*)(WTr + ((c0 + ct) * 16 + lrow) * H + ks * 32 + lk);
#pragma unroll
                for (int rt = 0; rt < 2; ++rt)
                    acc[rt][ct] = __builtin_amdgcn_mfma_f32_16x16x32_bf16(a[rt][ks], w, acc[rt][ct], 0, 0, 0);
            }
#pragma unroll
        for (int rt = 0; rt < 2; ++rt)
#pragma unroll
            for (int ct = 0; ct < 4; ++ct)
#pragma unroll
                for (int rg = 0; rg < 4; ++rg) {
                    int lr = rt * 16 + ((lane >> 4) << 2) + rg;
                    hls[wave][lr][(c0 + ct) * 16 + lrow] = f2bf(lrelu(acc[rt][ct][rg]));
                }
    }

    // ---- stage 2: A-fragments from LDS (wave-private; lgkmcnt orders) ----
    short8 a2[2][4];
#pragma unroll
    for (int rt = 0; rt < 2; ++rt)
#pragma unroll
        for (int ks = 0; ks < 4; ++ks)
            a2[rt][ks] = *(const short8*)&hls[wave][rt * 16 + lrow][ks * 32 + lk];

#pragma unroll
    for (int pass = 0; pass < 4; ++pass) {
        const unsigned short* W = (pass < 2) ? WTq : WTk;
        const float* b = (pass < 2) ? bq : bk;
        unsigned short* o = (pass < 2) ? q : k;
        int c0 = (pass & 1) * 4;
        fx4 acc[2][4];
#pragma unroll
        for (int ct = 0; ct < 4; ++ct) {
            float v = b[(c0 + ct) * 16 + lrow];
#pragma unroll
            for (int rt = 0; rt < 2; ++rt) acc[rt][ct] = fx4{v, v, v, v};
        }
#pragma unroll
        for (int ks = 0; ks < 4; ++ks)
#pragma unroll
            for (int ct = 0; ct < 4; ++ct) {
                short8 w = *(const short8*)(W + ((c0 + ct) * 16 + lrow) * H + ks * 32 + lk);
#pragma unroll
                for (int rt = 0; rt < 2; ++rt)
                    acc[rt][ct] = __builtin_amdgcn_mfma_f32_16x16x32_bf16(a2[rt][ks], w, acc[rt][ct], 0, 0, 0);
            }
#pragma unroll
        for (int rt = 0; rt < 2; ++rt)
#pragma unroll
            for (int ct = 0; ct < 4; ++ct)
#pragma unroll
                for (int rg = 0; rg < 4; ++rg) {
                    int r = row0 + rt * 16 + ((lane >> 4) << 2) + rg;
                    if (r < NN)
                        o[(size_t)r * H + (c0 + ct) * 16 + lrow] = f2bf(acc[rt][ct][rg]);
                }
    }
}

// ---------------- aggregation: 16 gathers per iter group (4 in flight per lane) ----------------
// All __shfl wave-uniform; indices provably <= 63; loads unconditional on valid dummy row 0.
__global__ __launch_bounds__(256) void k_agg(const unsigned short* __restrict__ q,
                                             const unsigned short* __restrict__ kk,
                                             const int* __restrict__ rowp,
                                             const int* __restrict__ csr_src,
                                             unsigned short* __restrict__ agg) {
    int node = blockIdx.x * 4 + (threadIdx.x >> 6);
    if (node >= NN) return;
    int lane = threadIdx.x & 63;
    int qt = lane >> 4;
    int ql = lane & 15;
    int start = rowp[node];
    int end = rowp[node + 1];

    uint4 qp = *(const uint4*)(q + (size_t)node * H + ql * 8);
    float qv0 = bflo(qp.x), qv1 = bfhi(qp.x), qv2 = bflo(qp.y), qv3 = bfhi(qp.y);
    float qv4 = bflo(qp.z), qv5 = bfhi(qp.z), qv6 = bflo(qp.w), qv7 = bfhi(qp.w);
    float a0 = 0.f, a1 = 0.f, a2 = 0.f, a3 = 0.f, a4 = 0.f, a5 = 0.f, a6 = 0.f, a7 = 0.f;

    for (int base = start; base < end; base += 64) {
        int cnt = end - base;
        if (cnt > 64) cnt = 64;
        int sid = (lane < cnt) ? csr_src[base + lane] : 0;
        int cnt16 = (cnt + 15) & ~15;
        for (int j = 0; j < cnt16; j += 16) {
            int jj0 = j + qt;        // <= 63
            int jj1 = j + 4 + qt;
            int jj2 = j + 8 + qt;
            int jj3 = j + 12 + qt;   // <= cnt16-16+12+3 <= 63
            int s0 = __shfl(sid, jj0);
            int s1 = __shfl(sid, jj1);
            int s2 = __shfl(sid, jj2);
            int s3 = __shfl(sid, jj3);
            uint4 kp0 = *(const uint4*)(kk + (size_t)s0 * H + ql * 8);
            uint4 kp1 = *(const uint4*)(kk + (size_t)s1 * H + ql * 8);
            uint4 kp2 = *(const uint4*)(kk + (size_t)s2 * H + ql * 8);
            uint4 kp3 = *(const uint4*)(kk + (size_t)s3 * H + ql * 8);
            if (jj0 < cnt) {
                a0 += lrelu(qv0 + bflo(kp0.x)); a1 += lrelu(qv1 + bfhi(kp0.x));
                a2 += lrelu(qv2 + bflo(kp0.y)); a3 += lrelu(qv3 + bfhi(kp0.y));
                a4 += lrelu(qv4 + bflo(kp0.z)); a5 += lrelu(qv5 + bfhi(kp0.z));
                a6 += lrelu(qv6 + bflo(kp0.w)); a7 += lrelu(qv7 + bfhi(kp0.w));
            }
            if (jj1 < cnt) {
                a0 += lrelu(qv0 + bflo(kp1.x)); a1 += lrelu(qv1 + bfhi(kp1.x));
                a2 += lrelu(qv2 + bflo(kp1.y)); a3 += lrelu(qv3 + bfhi(kp1.y));
                a4 += lrelu(qv4 + bflo(kp1.z)); a5 += lrelu(qv5 + bfhi(kp1.z));
                a6 += lrelu(qv6 + bflo(kp1.w)); a7 += lrelu(qv7 + bfhi(kp1.w));
            }
            if (jj2 < cnt) {
                a0 += lrelu(qv0 + bflo(kp2.x)); a1 += lrelu(qv1 + bfhi(kp2.x));
                a2 += lrelu(qv2 + bflo(kp2.y)); a3 += lrelu(qv3 + bfhi(kp2.y));
                a4 += lrelu(qv4 + bflo(kp2.z)); a5 += lrelu(qv5 + bfhi(kp2.z));
                a6 += lrelu(qv6 + bflo(kp2.w)); a7 += lrelu(qv7 + bfhi(kp2.w));
            }
            if (jj3 < cnt) {
                a0 += lrelu(qv0 + bflo(kp3.x)); a1 += lrelu(qv1 + bfhi(kp3.x));
                a2 += lrelu(qv2 + bflo(kp3.y)); a3 += lrelu(qv3 + bfhi(kp3.y));
                a4 += lrelu(qv4 + bflo(kp3.z)); a5 += lrelu(qv5 + bfhi(kp3.z));
                a6 += lrelu(qv6 + bflo(kp3.w)); a7 += lrelu(qv7 + bfhi(kp3.w));
            }
        }
    }
    a0 += __shfl_xor(a0, 16); a0 += __shfl_xor(a0, 32);
    a1 += __shfl_xor(a1, 16); a1 += __shfl_xor(a1, 32);
    a2 += __shfl_xor(a2, 16); a2 += __shfl_xor(a2, 32);
    a3 += __shfl_xor(a3, 16); a3 += __shfl_xor(a3, 32);
    a4 += __shfl_xor(a4, 16); a4 += __shfl_xor(a4, 32);
    a5 += __shfl_xor(a5, 16); a5 += __shfl_xor(a5, 32);
    a6 += __shfl_xor(a6, 16); a6 += __shfl_xor(a6, 32);
    a7 += __shfl_xor(a7, 16); a7 += __shfl_xor(a7, 32);
    if (qt == 0) {
        uint4 o;
        o.x = (unsigned int)f2bf(a0) | ((unsigned int)f2bf(a1) << 16);
        o.y = (unsigned int)f2bf(a2) | ((unsigned int)f2bf(a3) << 16);
        o.z = (unsigned int)f2bf(a4) | ((unsigned int)f2bf(a5) << 16);
        o.w = (unsigned int)f2bf(a6) | ((unsigned int)f2bf(a7) << 16);
        *(uint4*)(agg + (size_t)node * H + ql * 8) = o;
    }
}

// ---------------- segmented graph pooling ----------------
__global__ __launch_bounds__(256) void k_pool_seg(const unsigned short* __restrict__ h,
                                                  const int* __restrict__ gstart,
                                                  float* __restrict__ hg) {
    int g = blockIdx.x * 4 + (threadIdx.x >> 6);
    if (g >= NG) return;
    int lane = threadIdx.x & 63;
    int s = gstart[g], e = gstart[g + 1];
    float ax = 0.f, ay = 0.f;
    for (int n = s; n < e; ++n) {
        unsigned int hp = *(const unsigned int*)(h + (size_t)n * H + lane * 2);
        ax += bflo(hp);
        ay += bfhi(hp);
    }
    float2 o;
    o.x = ax;
    o.y = ay;
    *(float2*)(hg + (size_t)g * H + lane * 2) = o;
}

// ---------------- MLP head ----------------
__global__ __launch_bounds__(256) void k_mlp1(const float* __restrict__ hg,
                                              const float* __restrict__ W1,
                                              const float* __restrict__ b1,
                                              float* __restrict__ x1) {
    __shared__ float W1s[128 * 64];
    __shared__ float hgs[4 * 128];
    int t = threadIdx.x;
    int g0 = blockIdx.x * 4;
#pragma unroll
    for (int i = 0; i < 32; ++i) W1s[t + i * 256] = W1[t + i * 256];
    for (int i = t; i < 4 * 128; i += 256) hgs[i] = hg[(size_t)g0 * H + i];
    __syncthreads();
    int g = t >> 6, c = t & 63;
    float acc = b1[c];
    const float* row = hgs + g * 128;
    for (int j = 0; j < 128; ++j) acc += row[j] * W1s[j * 64 + c];
    x1[(g0 + g) * 64 + c] = acc;
}

template <int C>
__global__ __launch_bounds__(1024) void k_bnstats(const float* __restrict__ x,
                                                  float* __restrict__ stats) {
    __shared__ float red[1024];
    __shared__ float mus[C];
    int t = threadIdx.x;
    int c = t & (C - 1), rc = t / C;
    const int R = 1024 / C;
    float s = 0.f;
    for (int g = rc; g < NG; g += R) s += x[g * C + c];
    red[t] = s;
    __syncthreads();
    if (t < C) {
        float S = 0.f;
        for (int i = 0; i < R; ++i) S += red[i * C + t];
        float mu = S / NG;
        mus[t] = mu;
        stats[t] = mu;
    }
    __syncthreads();
    float mu = mus[c];
    float s2 = 0.f;
    for (int g = rc; g < NG; g += R) {
        float d = x[g * C + c] - mu;
        s2 += d * d;
    }
    red[t] = s2;
    __syncthreads();
    if (t < C) {
        float Q = 0.f;
        for (int i = 0; i < R; ++i) Q += red[i * C + t];
        stats[C + t] = rsqrtf(Q / NG + 1e-5f);
    }
}

__global__ __launch_bounds__(256) void k_mlp2f(const float* __restrict__ x1,
                                               const float* __restrict__ st,
                                               const float* __restrict__ g1,
                                               const float* __restrict__ be1,
                                               const float* __restrict__ W2,
                                               const float* __restrict__ b2,
                                               float* __restrict__ x2) {
    __shared__ float W2s[64 * 32];
    __shared__ float x1s[8 * 64];
    int t = threadIdx.x;
    int g0 = blockIdx.x * 8;
#pragma unroll
    for (int i = 0; i < 8; ++i) W2s[t + i * 256] = W2[t + i * 256];
#pragma unroll
    for (int i = 0; i < 2; ++i) {
        int idx = t + i * 256;
        int c = idx & 63;
        float v = x1[(size_t)g0 * 64 + idx];
        v = (v - st[c]) * st[64 + c] * g1[c] + be1[c];
        x1s[idx] = lrelu(v);
    }
    __syncthreads();
    int g = t >> 5, c = t & 31;
    float acc = b2[c];
    const float* row = x1s + g * 64;
    for (int j = 0; j < 64; ++j) acc += row[j] * W2s[j * 32 + c];
    x2[(g0 + g) * 32 + c] = acc;
}

__global__ __launch_bounds__(256) void k_mlp3f(const float* __restrict__ x2,
                                               const float* __restrict__ st,
                                               const float* __restrict__ g2,
                                               const float* __restrict__ be2,
                                               const float* __restrict__ W3,
                                               const float* __restrict__ b3,
                                               float* __restrict__ out) {
    int g = blockIdx.x * blockDim.x + threadIdx.x;
    if (g >= NG) return;
    float acc = b3[0];
    for (int j = 0; j < 32; ++j) {
        float v = (x2[g * 32 + j] - st[j]) * st[32 + j] * g2[j] + be2[j];
        acc += lrelu(v) * W3[j];
    }
    out[g] = acc;
}

extern "C" void kernel_launch(void* const* d_in, const int* in_sizes, int n_in,
                              void* d_out, int out_size, void* d_ws, size_t ws_size,
                              hipStream_t stream) {
    const int* nfeats = (const int*)d_in[0];
    const int* src = (const int*)d_in[2];
    const int* dst = (const int*)d_in[3];
    const int* gid = (const int*)d_in[4];
    const float* emb = (const float*)d_in[5];
    const float* Wq = (const float*)d_in[6];
    const float* bq = (const float*)d_in[7];
    const float* Wk = (const float*)d_in[8];
    const float* bk = (const float*)d_in[9];
    const float* Wr = (const float*)d_in[10];
    const float* br = (const float*)d_in[11];
    const float* W1 = (const float*)d_in[12];
    const float* b1 = (const float*)d_in[13];
    const float* g1 = (const float*)d_in[14];
    const float* be1 = (const float*)d_in[15];
    const float* W2 = (const float*)d_in[16];
    const float* b2 = (const float*)d_in[17];
    const float* g2 = (const float*)d_in[18];
    const float* be2 = (const float*)d_in[19];
    const float* W3 = (const float*)d_in[20];
    const float* b3 = (const float*)d_in[21];
    float* out = (float*)d_out;

    size_t nh = (size_t)NP * H;
    unsigned short* P0 = (unsigned short*)d_ws;
    unsigned short* P1 = P0 + nh;
    unsigned short* P2 = P1 + nh;
    unsigned short* WT = P2 + nh;
    float* hg = (float*)(WT + 12 * H * H);
    float* x1 = hg + (size_t)NG * H;
    float* x2 = x1 + (size_t)NG * 64;
    float* st = x2 + (size_t)NG * 32;
    int* cursor = (int*)(st + 2 * 64);
    int* rowp = cursor + NN;
    int* bsum = rowp + NN + 1;
    int* csr_src = bsum + 128;
    int* gstart = csr_src + NE;

    // ---- CSR build + graph boundaries ----
    hipMemsetAsync(cursor, 0, NN * sizeof(int), stream);
    k_hist<<<(NE / 4 + 255) / 256, 256, 0, stream>>>(dst, cursor);
    k_scan1<<<SCAN_BLOCKS, 1024, 0, stream>>>(cursor, rowp, bsum);
    k_scan2<<<1, 128, 0, stream>>>(bsum);
    k_scan3g<<<SCAN3_BLOCKS + 4, 256, 0, stream>>>(bsum, rowp, cursor, gid, gstart);
    k_scatter<<<(NE / 4 + 255) / 256, 256, 0, stream>>>(src, dst, cursor, csr_src);

    // ---- weight prep ----
    k_wt<<<12, 256, 0, stream>>>(Wq, Wk, Wr, WT);

    const int NB = NP / 128;  // 782
    // layer 0 q/k, atom encoder fused (h never materialized)
    k_aqk_mfma<<<NB, 256, 0, stream>>>(nfeats, emb, WT + 0 * H * H, bq, WT + 1 * H * H, bk, P1, P2);
    for (int l = 0; l < NLAYER; ++l) {
        k_agg<<<(NN + 3) / 4, 256, 0, stream>>>(P1, P2, rowp, csr_src, P0);
        if (l < NLAYER - 1) {
            k_rqk_mfma<<<NB, 256, 0, stream>>>(P0, WT + (size_t)(l * 3 + 2) * H * H, br + l * H,
                                               WT + (size_t)((l + 1) * 3 + 0) * H * H, bq + (l + 1) * H,
                                               WT + (size_t)((l + 1) * 3 + 1) * H * H, bk + (l + 1) * H,
                                               P1, P2);
        } else {
            k_r_mfma<<<NB, 256, 0, stream>>>(P0, WT + (size_t)(l * 3 + 2) * H * H, br + l * H, P1);
        }
    }

    k_pool_seg<<<(NG + 3) / 4, 256, 0, stream>>>(P1, gstart, hg);

    // ---- MLP head ----
    k_mlp1<<<NG / 4, 256, 0, stream>>>(hg, W1, b1, x1);
    k_bnstats<64><<<1, 1024, 0, stream>>>(x1, st);
    k_mlp2f<<<NG / 8, 256, 0, stream>>>(x1, st, g1, be1, W2, b2, x2);
    k_bnstats<32><<<1, 1024, 0, stream>>>(x2, st);
    k_mlp3f<<<(NG + 255) / 256, 256, 0, stream>>>(x2, st, g2, be2, W3, b3, out);
}

// Round 10
// 673.978 us; speedup vs baseline: 2.8223x; 1.0837x over previous
//
#include <hip/hip_runtime.h>

#define NN 100000
#define NP 100096   // padded rows (782 blocks * 128)
#define NE 1000000
#define NG 1000
#define H 128
#define NLAYER 4
#define NEG 0.2f
#define SCAN_BLOCKS 98

using short8 = __attribute__((ext_vector_type(8))) short;
using fx4 = __attribute__((ext_vector_type(4))) float;

__device__ __forceinline__ float lrelu(float x) { return x >= 0.f ? x : NEG * x; }

__device__ __forceinline__ unsigned short f2bf(float f) {
    union { float f; unsigned int u; } v;
    v.f = f;
    return (unsigned short)((v.u + 0x7fffu + ((v.u >> 16) & 1u)) >> 16);
}
__device__ __forceinline__ float bflo(unsigned int u) {
    union { unsigned int x; float f; } v;
    v.x = u << 16;
    return v.f;
}
__device__ __forceinline__ float bfhi(unsigned int u) {
    union { unsigned int x; float f; } v;
    v.x = u & 0xffff0000u;
    return v.f;
}

// ---------------- Weight prep ----------------
__global__ __launch_bounds__(256) void k_wt(const float* __restrict__ Wq,
                                            const float* __restrict__ Wk,
                                            const float* __restrict__ Wr,
                                            unsigned short* __restrict__ WT) {
    int mat = blockIdx.x;
    int l = mat / 3;
    int kind = mat - l * 3;
    const float* src = (kind == 0 ? Wq : kind == 1 ? Wk : Wr) + (size_t)l * H * H;
    unsigned short* dst = WT + (size_t)mat * H * H;
    for (int idx = threadIdx.x; idx < H * H; idx += 256) {
        int kk = idx >> 7, n = idx & 127;
        dst[n * H + kk] = f2bf(src[idx]);
    }
}

// ---------------- CSR build ----------------
__global__ __launch_bounds__(256) void k_hist(const int* __restrict__ dst, int* __restrict__ deg) {
    int i = blockIdx.x * blockDim.x + threadIdx.x;
    if (i * 4 >= NE) return;
    int4 d = *(const int4*)(dst + i * 4);
    atomicAdd(&deg[d.x], 1);
    atomicAdd(&deg[d.y], 1);
    atomicAdd(&deg[d.z], 1);
    atomicAdd(&deg[d.w], 1);
}

__global__ __launch_bounds__(1024) void k_scan1(const int* __restrict__ deg,
                                                int* __restrict__ rowp,
                                                int* __restrict__ bsum) {
    __shared__ int tmp[1024];
    int t = threadIdx.x;
    int i = blockIdx.x * 1024 + t;
    int v = (i < NN) ? deg[i] : 0;
    tmp[t] = v;
    __syncthreads();
    for (int off = 1; off < 1024; off <<= 1) {
        int u = (t >= off) ? tmp[t - off] : 0;
        __syncthreads();
        tmp[t] += u;
        __syncthreads();
    }
    if (i < NN) rowp[i] = tmp[t] - v;
    if (t == 1023) bsum[blockIdx.x] = tmp[1023];
}

__global__ __launch_bounds__(128) void k_scan2(int* __restrict__ bsum) {
    __shared__ int tmp[128];
    int t = threadIdx.x;
    int v = (t < SCAN_BLOCKS) ? bsum[t] : 0;
    tmp[t] = v;
    __syncthreads();
    for (int off = 1; off < 128; off <<= 1) {
        int u = (t >= off) ? tmp[t - off] : 0;
        __syncthreads();
        tmp[t] += u;
        __syncthreads();
    }
    if (t < SCAN_BLOCKS) bsum[t] = tmp[t] - v;
}

#define SCAN3_BLOCKS ((NN + 255) / 256)
__global__ __launch_bounds__(256) void k_scan3g(const int* __restrict__ bsum,
                                                int* __restrict__ rowp,
                                                int* __restrict__ cursor,
                                                const int* __restrict__ gid,
                                                int* __restrict__ gstart) {
    int bid = blockIdx.x;
    int t = threadIdx.x;
    if (bid < SCAN3_BLOCKS) {
        int i = bid * 256 + t;
        if (i < NN) {
            int v = rowp[i] + bsum[i >> 10];
            rowp[i] = v;
            cursor[i] = v;
        }
        if (i == 0) rowp[NN] = NE;
    } else {
        int g = (bid - SCAN3_BLOCKS) * 256 + t;
        if (g > NG) return;
        if (g == NG) { gstart[NG] = NN; return; }
        int lo = 0, hi = NN;
        while (lo < hi) {
            int mid = (lo + hi) >> 1;
            if (gid[mid] < g) lo = mid + 1; else hi = mid;
        }
        gstart[g] = lo;
    }
}

__global__ __launch_bounds__(256) void k_scatter(const int* __restrict__ src,
                                                 const int* __restrict__ dst,
                                                 int* __restrict__ cursor,
                                                 int* __restrict__ csr_src) {
    int i = blockIdx.x * blockDim.x + threadIdx.x;
    if (i * 4 >= NE) return;
    int4 s = *(const int4*)(src + i * 4);
    int4 d = *(const int4*)(dst + i * 4);
    csr_src[atomicAdd(&cursor[d.x], 1)] = s.x;
    csr_src[atomicAdd(&cursor[d.y], 1)] = s.y;
    csr_src[atomicAdd(&cursor[d.z], 1)] = s.z;
    csr_src[atomicAdd(&cursor[d.w], 1)] = s.w;
}

// ============ shared helpers for MFMA kernels (macros keep code identical across kernels) ============
// C-fragment -> LDS staging (values f2bf'd), layout: S[row][col], row stride 136 ushort (272B, 16B-aligned)
// copy-out of a 64-col half: 4 steps, lane -> chunk (row=c>>3, off=(c&7)*8)
// copy-out of full 128 cols: 8 steps, chunk (row=c>>4, off=(c&15)*8)

// ---------------- FUSED atom encoder + layer-0 q/k GEMM ----------------
// Wave encodes its 32 rows into wave-private LDS (coalesced, bit-exact vs k_atom),
// reads A-fragments from LDS, then GEMM passes with LDS-staged coalesced stores.
__global__ __launch_bounds__(256) void k_aqk_mfma(const int* __restrict__ nfeats,
                                                  const float* __restrict__ emb,
                                                  const unsigned short* __restrict__ WTq,
                                                  const float* __restrict__ bq,
                                                  const unsigned short* __restrict__ WTk,
                                                  const float* __restrict__ bk,
                                                  unsigned short* __restrict__ q,
                                                  unsigned short* __restrict__ k) {
    __shared__ unsigned short hls[4][32][136];
    int lane = threadIdx.x & 63;
    int wave = threadIdx.x >> 6;
    int row0 = blockIdx.x * 128 + wave * 32;
    int lrow = lane & 15;
    int lk = (lane >> 4) << 3;
    unsigned short (*S)[136] = hls[wave];

    // ---- atom encode: 32 rows, coalesced 512B embedding reads per (row,f) ----
    {
        int c = lane * 2;
        for (int rr = 0; rr < 32; ++rr) {
            int row = row0 + rr;
            int crow = row < NN ? row : NN - 1;
            float ax = 0.f, ay = 0.f;
#pragma unroll
            for (int f = 0; f < 9; ++f) {
                int idx = nfeats[crow * 9 + f];
                float2 e = *(const float2*)(emb + (size_t)((f << 6) + idx) * H + c);
                ax += e.x;
                ay += e.y;
            }
            *(unsigned int*)&S[rr][c] = (unsigned int)f2bf(ax) | ((unsigned int)f2bf(ay) << 16);
        }
    }

    // ---- A-fragments from LDS ----
    short8 a[2][4];
#pragma unroll
    for (int rt = 0; rt < 2; ++rt)
#pragma unroll
        for (int ks = 0; ks < 4; ++ks)
            a[rt][ks] = *(const short8*)&S[rt * 16 + lrow][ks * 32 + lk];

    // ---- 4 passes: {q,k} x {cols 0-63, 64-127}; S reused as output staging ----
#pragma unroll
    for (int pass = 0; pass < 4; ++pass) {
        const unsigned short* W = (pass < 2) ? WTq : WTk;
        const float* b = (pass < 2) ? bq : bk;
        unsigned short* o = (pass < 2) ? q : k;
        int c0 = (pass & 1) * 4;
        fx4 acc[2][4];
#pragma unroll
        for (int ct = 0; ct < 4; ++ct) {
            float v = b[(c0 + ct) * 16 + lrow];
#pragma unroll
            for (int rt = 0; rt < 2; ++rt) acc[rt][ct] = fx4{v, v, v, v};
        }
#pragma unroll
        for (int ks = 0; ks < 4; ++ks)
#pragma unroll
            for (int ct = 0; ct < 4; ++ct) {
                short8 w = *(const short8*)(W + ((c0 + ct) * 16 + lrow) * H + ks * 32 + lk);
#pragma unroll
                for (int rt = 0; rt < 2; ++rt)
                    acc[rt][ct] = __builtin_amdgcn_mfma_f32_16x16x32_bf16(a[rt][ks], w, acc[rt][ct], 0, 0, 0);
            }
        // stage C-fragments to LDS (scattered 2B writes are cheap in LDS)
#pragma unroll
        for (int rt = 0; rt < 2; ++rt)
#pragma unroll
            for (int ct = 0; ct < 4; ++ct)
#pragma unroll
                for (int rg = 0; rg < 4; ++rg)
                    S[rt * 16 + ((lane >> 4) << 2) + rg][(c0 + ct) * 16 + lrow] = f2bf(acc[rt][ct][rg]);
        // coalesced copy-out: 32 rows x 64 cols
#pragma unroll
        for (int step = 0; step < 4; ++step) {
            int cch = step * 64 + lane;
            int r = cch >> 3;
            int off = c0 * 16 + (cch & 7) * 8;
            int gr = row0 + r;
            if (gr < NN)
                *(uint4*)(o + (size_t)gr * H + off) = *(const uint4*)&S[r][off];
        }
    }
}

// ---------------- h_new = lrelu(agg@Wr + br) (final layer), LDS-staged stores ----------------
__global__ __launch_bounds__(256) void k_r_mfma(const unsigned short* __restrict__ agg,
                                                const unsigned short* __restrict__ WTr,
                                                const float* __restrict__ br,
                                                unsigned short* __restrict__ hout) {
    __shared__ unsigned short hls[4][32][136];
    int lane = threadIdx.x & 63;
    int wave = threadIdx.x >> 6;
    int row0 = blockIdx.x * 128 + wave * 32;
    int lrow = lane & 15;
    int lk = (lane >> 4) << 3;
    unsigned short (*S)[136] = hls[wave];

    short8 a[2][4];
#pragma unroll
    for (int rt = 0; rt < 2; ++rt)
#pragma unroll
        for (int ks = 0; ks < 4; ++ks)
            a[rt][ks] = *(const short8*)(agg + (size_t)(row0 + rt * 16 + lrow) * H + ks * 32 + lk);

#pragma unroll
    for (int chf = 0; chf < 2; ++chf) {
        int c0 = chf * 4;
        fx4 acc[2][4];
#pragma unroll
        for (int ct = 0; ct < 4; ++ct) {
            float v = br[(c0 + ct) * 16 + lrow];
#pragma unroll
            for (int rt = 0; rt < 2; ++rt) acc[rt][ct] = fx4{v, v, v, v};
        }
#pragma unroll
        for (int ks = 0; ks < 4; ++ks)
#pragma unroll
            for (int ct = 0; ct < 4; ++ct) {
                short8 w = *(const short8*)(WTr + ((c0 + ct) * 16 + lrow) * H + ks * 32 + lk);
#pragma unroll
                for (int rt = 0; rt < 2; ++rt)
                    acc[rt][ct] = __builtin_amdgcn_mfma_f32_16x16x32_bf16(a[rt][ks], w, acc[rt][ct], 0, 0, 0);
            }
#pragma unroll
        for (int rt = 0; rt < 2; ++rt)
#pragma unroll
            for (int ct = 0; ct < 4; ++ct)
#pragma unroll
                for (int rg = 0; rg < 4; ++rg)
                    S[rt * 16 + ((lane >> 4) << 2) + rg][(c0 + ct) * 16 + lrow] = f2bf(lrelu(acc[rt][ct][rg]));
    }
    // coalesced copy-out: 32 rows x 128 cols
#pragma unroll
    for (int step = 0; step < 8; ++step) {
        int cch = step * 64 + lane;
        int r = cch >> 4;
        int off = (cch & 15) * 8;
        int gr = row0 + r;
        if (gr < NN)
            *(uint4*)(hout + (size_t)gr * H + off) = *(const uint4*)&S[r][off];
    }
}

// ---------------- FUSED: h_new = lrelu(agg@Wr+br); q = h_new@Wq+bq; k = h_new@Wk+bk ----------------
__global__ __launch_bounds__(256) void k_rqk_mfma(const unsigned short* __restrict__ agg,
                                                  const unsigned short* __restrict__ WTr,
                                                  const float* __restrict__ br,
                                                  const unsigned short* __restrict__ WTq,
                                                  const float* __restrict__ bq,
                                                  const unsigned short* __restrict__ WTk,
                                                  const float* __restrict__ bk,
                                                  unsigned short* __restrict__ q,
                                                  unsigned short* __restrict__ k) {
    __shared__ unsigned short hls[4][32][136];
    int lane = threadIdx.x & 63;
    int wave = threadIdx.x >> 6;
    int row0 = blockIdx.x * 128 + wave * 32;
    int lrow = lane & 15;
    int lk = (lane >> 4) << 3;
    unsigned short (*S)[136] = hls[wave];

    // ---- stage 1: h_new = lrelu(agg @ Wr + br) -> LDS ----
    short8 a[2][4];
#pragma unroll
    for (int rt = 0; rt < 2; ++rt)
#pragma unroll
        for (int ks = 0; ks < 4; ++ks)
            a[rt][ks] = *(const short8*)(agg + (size_t)(row0 + rt * 16 + lrow) * H + ks * 32 + lk);

#pragma unroll
    for (int chf = 0; chf < 2; ++chf) {
        int c0 = chf * 4;
        fx4 acc[2][4];
#pragma unroll
        for (int ct = 0; ct < 4; ++ct) {
            float v = br[(c0 + ct) * 16 + lrow];
#pragma unroll
            for (int rt = 0; rt < 2; ++rt) acc[rt][ct] = fx4{v, v, v, v};
        }
#pragma unroll
        for (int ks = 0; ks < 4; ++ks)
#pragma unroll
            for (int ct = 0; ct < 4; ++ct) {
                short8 w = *(const short8*)(WTr + ((c0 + ct) * 16 + lrow) * H + ks * 32 + lk);
#pragma unroll
                for (int rt = 0; rt < 2; ++rt)
                    acc[rt][ct] = __builtin_amdgcn_mfma_f32_16x16x32_bf16(a[rt][ks], w, acc[rt][ct], 0, 0, 0);
            }
#pragma unroll
        for (int rt = 0; rt < 2; ++rt)
#pragma unroll
            for (int ct = 0; ct < 4; ++ct)
#pragma unroll
                for (int rg = 0; rg < 4; ++rg)
                    S[rt * 16 + ((lane >> 4) << 2) + rg][(c0 + ct) * 16 + lrow] = f2bf(lrelu(acc[rt][ct][rg]));
    }

    // ---- stage 2: A-fragments of h_new from LDS ----
    short8 a2[2][4];
#pragma unroll
    for (int rt = 0; rt < 2; ++rt)
#pragma unroll
        for (int ks = 0; ks < 4; ++ks)
            a2[rt][ks] = *(const short8*)&S[rt * 16 + lrow][ks * 32 + lk];

    // ---- 4 passes with LDS-staged coalesced stores (S reused after a2 loads) ----
#pragma unroll
    for (int pass = 0; pass < 4; ++pass) {
        const unsigned short* W = (pass < 2) ? WTq : WTk;
        const float* b = (pass < 2) ? bq : bk;
        unsigned short* o = (pass < 2) ? q : k;
        int c0 = (pass & 1) * 4;
        fx4 acc[2][4];
#pragma unroll
        for (int ct = 0; ct < 4; ++ct) {
            float v = b[(c0 + ct) * 16 + lrow];
#pragma unroll
            for (int rt = 0; rt < 2; ++rt) acc[rt][ct] = fx4{v, v, v, v};
        }
#pragma unroll
        for (int ks = 0; ks < 4; ++ks)
#pragma unroll
            for (int ct = 0; ct < 4; ++ct) {
                short8 w = *(const short8*)(W + ((c0 + ct) * 16 + lrow) * H + ks * 32 + lk);
#pragma unroll
                for (int rt = 0; rt < 2; ++rt)
                    acc[rt][ct] = __builtin_amdgcn_mfma_f32_16x16x32_bf16(a2[rt][ks], w, acc[rt][ct], 0, 0, 0);
            }
#pragma unroll
        for (int rt = 0; rt < 2; ++rt)
#pragma unroll
            for (int ct = 0; ct < 4; ++ct)
#pragma unroll
                for (int rg = 0; rg < 4; ++rg)
                    S[rt * 16 + ((lane >> 4) << 2) + rg][(c0 + ct) * 16 + lrow] = f2bf(acc[rt][ct][rg]);
#pragma unroll
        for (int step = 0; step < 4; ++step) {
            int cch = step * 64 + lane;
            int r = cch >> 3;
            int off = c0 * 16 + (cch & 7) * 8;
            int gr = row0 + r;
            if (gr < NN)
                *(uint4*)(o + (size_t)gr * H + off) = *(const uint4*)&S[r][off];
        }
    }
}

// ---------------- aggregation: 16 gathers per iter group (4 in flight per lane) ----------------
__global__ __launch_bounds__(256) void k_agg(const unsigned short* __restrict__ q,
                                             const unsigned short* __restrict__ kk,
                                             const int* __restrict__ rowp,
                                             const int* __restrict__ csr_src,
                                             unsigned short* __restrict__ agg) {
    int node = blockIdx.x * 4 + (threadIdx.x >> 6);
    if (node >= NN) return;
    int lane = threadIdx.x & 63;
    int qt = lane >> 4;
    int ql = lane & 15;
    int start = rowp[node];
    int end = rowp[node + 1];

    uint4 qp = *(const uint4*)(q + (size_t)node * H + ql * 8);
    float qv0 = bflo(qp.x), qv1 = bfhi(qp.x), qv2 = bflo(qp.y), qv3 = bfhi(qp.y);
    float qv4 = bflo(qp.z), qv5 = bfhi(qp.z), qv6 = bflo(qp.w), qv7 = bfhi(qp.w);
    float a0 = 0.f, a1 = 0.f, a2 = 0.f, a3 = 0.f, a4 = 0.f, a5 = 0.f, a6 = 0.f, a7 = 0.f;

    for (int base = start; base < end; base += 64) {
        int cnt = end - base;
        if (cnt > 64) cnt = 64;
        int sid = (lane < cnt) ? csr_src[base + lane] : 0;
        int cnt16 = (cnt + 15) & ~15;
        for (int j = 0; j < cnt16; j += 16) {
            int jj0 = j + qt;
            int jj1 = j + 4 + qt;
            int jj2 = j + 8 + qt;
            int jj3 = j + 12 + qt;
            int s0 = __shfl(sid, jj0);
            int s1 = __shfl(sid, jj1);
            int s2 = __shfl(sid, jj2);
            int s3 = __shfl(sid, jj3);
            uint4 kp0 = *(const uint4*)(kk + (size_t)s0 * H + ql * 8);
            uint4 kp1 = *(const uint4*)(kk + (size_t)s1 * H + ql * 8);
            uint4 kp2 = *(const uint4*)(kk + (size_t)s2 * H + ql * 8);
            uint4 kp3 = *(const uint4*)(kk + (size_t)s3 * H + ql * 8);
            if (jj0 < cnt) {
                a0 += lrelu(qv0 + bflo(kp0.x)); a1 += lrelu(qv1 + bfhi(kp0.x));
                a2 += lrelu(qv2 + bflo(kp0.y)); a3 += lrelu(qv3 + bfhi(kp0.y));
                a4 += lrelu(qv4 + bflo(kp0.z)); a5 += lrelu(qv5 + bfhi(kp0.z));
                a6 += lrelu(qv6 + bflo(kp0.w)); a7 += lrelu(qv7 + bfhi(kp0.w));
            }
            if (jj1 < cnt) {
                a0 += lrelu(qv0 + bflo(kp1.x)); a1 += lrelu(qv1 + bfhi(kp1.x));
                a2 += lrelu(qv2 + bflo(kp1.y)); a3 += lrelu(qv3 + bfhi(kp1.y));
                a4 += lrelu(qv4 + bflo(kp1.z)); a5 += lrelu(qv5 + bfhi(kp1.z));
                a6 += lrelu(qv6 + bflo(kp1.w)); a7 += lrelu(qv7 + bfhi(kp1.w));
            }
            if (jj2 < cnt) {
                a0 += lrelu(qv0 + bflo(kp2.x)); a1 += lrelu(qv1 + bfhi(kp2.x));
                a2 += lrelu(qv2 + bflo(kp2.y)); a3 += lrelu(qv3 + bfhi(kp2.y));
                a4 += lrelu(qv4 + bflo(kp2.z)); a5 += lrelu(qv5 + bfhi(kp2.z));
                a6 += lrelu(qv6 + bflo(kp2.w)); a7 += lrelu(qv7 + bfhi(kp2.w));
            }
            if (jj3 < cnt) {
                a0 += lrelu(qv0 + bflo(kp3.x)); a1 += lrelu(qv1 + bfhi(kp3.x));
                a2 += lrelu(qv2 + bflo(kp3.y)); a3 += lrelu(qv3 + bfhi(kp3.y));
                a4 += lrelu(qv4 + bflo(kp3.z)); a5 += lrelu(qv5 + bfhi(kp3.z));
                a6 += lrelu(qv6 + bflo(kp3.w)); a7 += lrelu(qv7 + bfhi(kp3.w));
            }
        }
    }
    a0 += __shfl_xor(a0, 16); a0 += __shfl_xor(a0, 32);
    a1 += __shfl_xor(a1, 16); a1 += __shfl_xor(a1, 32);
    a2 += __shfl_xor(a2, 16); a2 += __shfl_xor(a2, 32);
    a3 += __shfl_xor(a3, 16); a3 += __shfl_xor(a3, 32);
    a4 += __shfl_xor(a4, 16); a4 += __shfl_xor(a4, 32);
    a5 += __shfl_xor(a5, 16); a5 += __shfl_xor(a5, 32);
    a6 += __shfl_xor(a6, 16); a6 += __shfl_xor(a6, 32);
    a7 += __shfl_xor(a7, 16); a7 += __shfl_xor(a7, 32);
    if (qt == 0) {
        uint4 o;
        o.x = (unsigned int)f2bf(a0) | ((unsigned int)f2bf(a1) << 16);
        o.y = (unsigned int)f2bf(a2) | ((unsigned int)f2bf(a3) << 16);
        o.z = (unsigned int)f2bf(a4) | ((unsigned int)f2bf(a5) << 16);
        o.w = (unsigned int)f2bf(a6) | ((unsigned int)f2bf(a7) << 16);
        *(uint4*)(agg + (size_t)node * H + ql * 8) = o;
    }
}

// ---------------- segmented graph pooling ----------------
__global__ __launch_bounds__(256) void k_pool_seg(const unsigned short* __restrict__ h,
                                                  const int* __restrict__ gstart,
                                                  float* __restrict__ hg) {
    int g = blockIdx.x * 4 + (threadIdx.x >> 6);
    if (g >= NG) return;
    int lane = threadIdx.x & 63;
    int s = gstart[g], e = gstart[g + 1];
    float ax = 0.f, ay = 0.f;
    for (int n = s; n < e; ++n) {
        unsigned int hp = *(const unsigned int*)(h + (size_t)n * H + lane * 2);
        ax += bflo(hp);
        ay += bfhi(hp);
    }
    float2 o;
    o.x = ax;
    o.y = ay;
    *(float2*)(hg + (size_t)g * H + lane * 2) = o;
}

// ---------------- MLP head ----------------
__global__ __launch_bounds__(256) void k_mlp1(const float* __restrict__ hg,
                                              const float* __restrict__ W1,
                                              const float* __restrict__ b1,
                                              float* __restrict__ x1) {
    __shared__ float W1s[128 * 64];
    __shared__ float hgs[4 * 128];
    int t = threadIdx.x;
    int g0 = blockIdx.x * 4;
#pragma unroll
    for (int i = 0; i < 32; ++i) W1s[t + i * 256] = W1[t + i * 256];
    for (int i = t; i < 4 * 128; i += 256) hgs[i] = hg[(size_t)g0 * H + i];
    __syncthreads();
    int g = t >> 6, c = t & 63;
    float acc = b1[c];
    const float* row = hgs + g * 128;
    for (int j = 0; j < 128; ++j) acc += row[j] * W1s[j * 64 + c];
    x1[(g0 + g) * 64 + c] = acc;
}

template <int C>
__global__ __launch_bounds__(1024) void k_bnstats(const float* __restrict__ x,
                                                  float* __restrict__ stats) {
    __shared__ float red[1024];
    __shared__ float mus[C];
    int t = threadIdx.x;
    int c = t & (C - 1), rc = t / C;
    const int R = 1024 / C;
    float s = 0.f;
    for (int g = rc; g < NG; g += R) s += x[g * C + c];
    red[t] = s;
    __syncthreads();
    if (t < C) {
        float S = 0.f;
        for (int i = 0; i < R; ++i) S += red[i * C + t];
        float mu = S / NG;
        mus[t] = mu;
        stats[t] = mu;
    }
    __syncthreads();
    float mu = mus[c];
    float s2 = 0.f;
    for (int g = rc; g < NG; g += R) {
        float d = x[g * C + c] - mu;
        s2 += d * d;
    }
    red[t] = s2;
    __syncthreads();
    if (t < C) {
        float Q = 0.f;
        for (int i = 0; i < R; ++i) Q += red[i * C + t];
        stats[C + t] = rsqrtf(Q / NG + 1e-5f);
    }
}

__global__ __launch_bounds__(256) void k_mlp2f(const float* __restrict__ x1,
                                               const float* __restrict__ st,
                                               const float* __restrict__ g1,
                                               const float* __restrict__ be1,
                                               const float* __restrict__ W2,
                                               const float* __restrict__ b2,
                                               float* __restrict__ x2) {
    __shared__ float W2s[64 * 32];
    __shared__ float x1s[8 * 64];
    int t = threadIdx.x;
    int g0 = blockIdx.x * 8;
#pragma unroll
    for (int i = 0; i < 8; ++i) W2s[t + i * 256] = W2[t + i * 256];
#pragma unroll
    for (int i = 0; i < 2; ++i) {
        int idx = t + i * 256;
        int c = idx & 63;
        float v = x1[(size_t)g0 * 64 + idx];
        v = (v - st[c]) * st[64 + c] * g1[c] + be1[c];
        x1s[idx] = lrelu(v);
    }
    __syncthreads();
    int g = t >> 5, c = t & 31;
    float acc = b2[c];
    const float* row = x1s + g * 64;
    for (int j = 0; j < 64; ++j) acc += row[j] * W2s[j * 32 + c];
    x2[(g0 + g) * 32 + c] = acc;
}

__global__ __launch_bounds__(256) void k_mlp3f(const float* __restrict__ x2,
                                               const float* __restrict__ st,
                                               const float* __restrict__ g2,
                                               const float* __restrict__ be2,
                                               const float* __restrict__ W3,
                                               const float* __restrict__ b3,
                                               float* __restrict__ out) {
    int g = blockIdx.x * blockDim.x + threadIdx.x;
    if (g >= NG) return;
    float acc = b3[0];
    for (int j = 0; j < 32; ++j) {
        float v = (x2[g * 32 + j] - st[j]) * st[32 + j] * g2[j] + be2[j];
        acc += lrelu(v) * W3[j];
    }
    out[g] = acc;
}

extern "C" void kernel_launch(void* const* d_in, const int* in_sizes, int n_in,
                              void* d_out, int out_size, void* d_ws, size_t ws_size,
                              hipStream_t stream) {
    const int* nfeats = (const int*)d_in[0];
    const int* src = (const int*)d_in[2];
    const int* dst = (const int*)d_in[3];
    const int* gid = (const int*)d_in[4];
    const float* emb = (const float*)d_in[5];
    const float* Wq = (const float*)d_in[6];
    const float* bq = (const float*)d_in[7];
    const float* Wk = (const float*)d_in[8];
    const float* bk = (const float*)d_in[9];
    const float* Wr = (const float*)d_in[10];
    const float* br = (const float*)d_in[11];
    const float* W1 = (const float*)d_in[12];
    const float* b1 = (const float*)d_in[13];
    const float* g1 = (const float*)d_in[14];
    const float* be1 = (const float*)d_in[15];
    const float* W2 = (const float*)d_in[16];
    const float* b2 = (const float*)d_in[17];
    const float* g2 = (const float*)d_in[18];
    const float* be2 = (const float*)d_in[19];
    const float* W3 = (const float*)d_in[20];
    const float* b3 = (const float*)d_in[21];
    float* out = (float*)d_out;

    size_t nh = (size_t)NP * H;
    unsigned short* P0 = (unsigned short*)d_ws;
    unsigned short* P1 = P0 + nh;
    unsigned short* P2 = P1 + nh;
    unsigned short* WT = P2 + nh;
    float* hg = (float*)(WT + 12 * H * H);
    float* x1 = hg + (size_t)NG * H;
    float* x2 = x1 + (size_t)NG * 64;
    float* st = x2 + (size_t)NG * 32;
    int* cursor = (int*)(st + 2 * 64);
    int* rowp = cursor + NN;
    int* bsum = rowp + NN + 1;
    int* csr_src = bsum + 128;
    int* gstart = csr_src + NE;

    // ---- CSR build + graph boundaries ----
    hipMemsetAsync(cursor, 0, NN * sizeof(int), stream);
    k_hist<<<(NE / 4 + 255) / 256, 256, 0, stream>>>(dst, cursor);
    k_scan1<<<SCAN_BLOCKS, 1024, 0, stream>>>(cursor, rowp, bsum);
    k_scan2<<<1, 128, 0, stream>>>(bsum);
    k_scan3g<<<SCAN3_BLOCKS + 4, 256, 0, stream>>>(bsum, rowp, cursor, gid, gstart);
    k_scatter<<<(NE / 4 + 255) / 256, 256, 0, stream>>>(src, dst, cursor, csr_src);

    // ---- weight prep ----
    k_wt<<<12, 256, 0, stream>>>(Wq, Wk, Wr, WT);

    const int NB = NP / 128;  // 782
    // layer 0 q/k, atom encoder fused (h never materialized)
    k_aqk_mfma<<<NB, 256, 0, stream>>>(nfeats, emb, WT + 0 * H * H, bq, WT + 1 * H * H, bk, P1, P2);
    for (int l = 0; l < NLAYER; ++l) {
        k_agg<<<(NN + 3) / 4, 256, 0, stream>>>(P1, P2, rowp, csr_src, P0);
        if (l < NLAYER - 1) {
            k_rqk_mfma<<<NB, 256, 0, stream>>>(P0, WT + (size_t)(l * 3 + 2) * H * H, br + l * H,
                                               WT + (size_t)((l + 1) * 3 + 0) * H * H, bq + (l + 1) * H,
                                               WT + (size_t)((l + 1) * 3 + 1) * H * H, bk + (l + 1) * H,
                                               P1, P2);
        } else {
            k_r_mfma<<<NB, 256, 0, stream>>>(P0, WT + (size_t)(l * 3 + 2) * H * H, br + l * H, P1);
        }
    }

    k_pool_seg<<<(NG + 3) / 4, 256, 0, stream>>>(P1, gstart, hg);

    // ---- MLP head ----
    k_mlp1<<<NG / 4, 256, 0, stream>>>(hg, W1, b1, x1);
    k_bnstats<64><<<1, 1024, 0, stream>>>(x1, st);
    k_mlp2f<<<NG / 8, 256, 0, stream>>>(x1, st, g1, be1, W2, b2, x2);
    k_bnstats<32><<<1, 1024, 0, stream>>>(x2, st);
    k_mlp3f<<<(NG + 255) / 256, 256, 0, stream>>>(x2, st, g2, be2, W3, b3, out);
}